// Round 20
// baseline (297.210 us; speedup 1.0000x reference)
//
#include <hip/hip_runtime.h>
#include <stdint.h>

typedef __attribute__((ext_vector_type(8))) __bf16 bf16x8;
typedef __attribute__((ext_vector_type(4))) float f32x4;

#define DEVI static __device__ __forceinline__

DEVI uint16_t f2b(float f) {
  uint32_t u = __float_as_uint(f);
  u += 0x7FFFu + ((u >> 16) & 1u);
  return (uint16_t)(u >> 16);
}
DEVI float b2f(uint16_t b) { return __uint_as_float(((uint32_t)b) << 16); }

DEVI void gl_lds16(const void* g, void* l) {
  __builtin_amdgcn_global_load_lds((const __attribute__((address_space(1))) void*)g,
                                   (__attribute__((address_space(3))) void*)l, 16, 0, 0);
}

DEVI f32x4 mfma16(bf16x8 a, bf16x8 b, f32x4 c) {
  return __builtin_amdgcn_mfma_f32_16x16x32_bf16(a, b, c, 0, 0, 0);
}

#define BARX asm volatile("s_barrier" ::: "memory")
#define WLG0 asm volatile("s_waitcnt lgkmcnt(0)" ::: "memory")
#define WV4 asm volatile("s_waitcnt vmcnt(4)" ::: "memory")
#define PRIO1 __builtin_amdgcn_s_setprio(1)
#define PRIO0 __builtin_amdgcn_s_setprio(0)

// ---------------- workspace layout (bf16 elements) ----------------
static constexpr size_t OFF_XB = 0;                       // 4096x2048 (reused as OBUF)
static constexpr size_t OFF_WD = 8388608;                 // 1792x2048 fused d-weights (pad rows zero)
static constexpr size_t OFF_WUKV = OFF_WD + 3670016;      // 4096x768
static constexpr size_t OFF_WUQR = OFF_WUKV + 3145728;    // 3072x768
static constexpr size_t OFF_WO = OFF_WUQR + 2359296;      // 2048x2048
static constexpr size_t OFF_CD = OFF_WO + 4194304;        // 4096x1792
static constexpr size_t OFF_CUKV = OFF_CD + 7340032;      // 4096x4096
static constexpr size_t OFF_CUQR = OFF_CUKV + 16777216;   // 4096x3072
static constexpr size_t OFF_VT = OFF_CUQR + 12582912;     // 32x128x2048

// ------- fused preprocessing: x cast + all 8 weight transposes (R11, measured-good) -------
__global__ void pre_kernel(const float* __restrict__ x, const float* __restrict__ Wdkv,
                           const float* __restrict__ Wuk, const float* __restrict__ Wuv,
                           const float* __restrict__ Wkr, const float* __restrict__ Wdq,
                           const float* __restrict__ Wuq, const float* __restrict__ Wqr,
                           const float* __restrict__ Wo, uint16_t* __restrict__ ws) {
  const int bid = blockIdx.x;
  const int t = threadIdx.x;
  if (bid >= 3264) {  // cast segment: 8192 blocks
    int id = (bid - 3264) * 256 + t;
    float4 v = ((const float4*)x)[id];
    uint16_t o[4] = {f2b(v.x), f2b(v.y), f2b(v.z), f2b(v.w)};
    *(uint64_t*)&ws[OFF_XB + (size_t)id * 4] = *(uint64_t*)o;
    return;
  }
  const float* W;
  uint16_t* Wt;
  int Kw, Nw, Kp, nx, rb;
  if (bid < 384) {
    W = Wdkv; Wt = ws + OFF_WD; Kw = 2048; Nw = 682; Kp = 2048; nx = 12; rb = bid;
  } else if (bid < 768) {
    W = Wdq; Wt = ws + OFF_WD + (size_t)768 * 2048; Kw = 2048; Nw = 682; Kp = 2048; nx = 12; rb = bid - 384;
  } else if (bid < 896) {
    W = Wkr; Wt = ws + OFF_WD + (size_t)1536 * 2048; Kw = 2048; Nw = 64; Kp = 2048; nx = 4; rb = bid - 768;
  } else if (bid < 1280) {
    W = Wuk; Wt = ws + OFF_WUKV; Kw = 682; Nw = 2048; Kp = 768; nx = 32; rb = bid - 896;
  } else if (bid < 1664) {
    W = Wuv; Wt = ws + OFF_WUKV + (size_t)2048 * 768; Kw = 682; Nw = 2048; Kp = 768; nx = 32; rb = bid - 1280;
  } else if (bid < 2048) {
    W = Wuq; Wt = ws + OFF_WUQR; Kw = 682; Nw = 2048; Kp = 768; nx = 32; rb = bid - 1664;
  } else if (bid < 2240) {
    W = Wqr; Wt = ws + OFF_WUQR + (size_t)2048 * 768; Kw = 682; Nw = 1024; Kp = 768; nx = 16; rb = bid - 2048;
  } else {
    W = Wo; Wt = ws + OFF_WO; Kw = 2048; Nw = 2048; Kp = 2048; nx = 32; rb = bid - 2240;
  }
  const int n0 = (rb % nx) * 64, k0 = (rb / nx) * 64;
  __shared__ uint16_t T[64][72];
#pragma unroll
  for (int p = 0; p < 2; ++p) {
    int r = p * 32 + (t >> 3);
    int c0 = (t & 7) * 8;
    int gr = k0 + r;
#pragma unroll
    for (int e = 0; e < 8; ++e) {
      int gc = n0 + c0 + e;
      float v = (gr < Kw && gc < Nw) ? W[(size_t)gr * Nw + gc] : 0.f;
      T[c0 + e][r] = f2b(v);
    }
  }
  __syncthreads();
#pragma unroll
  for (int p = 0; p < 2; ++p) {
    int dr = p * 32 + (t >> 3);
    int mc = (t & 7) * 8;
    uint16_t tmp[8];
#pragma unroll
    for (int e = 0; e < 8; ++e) tmp[e] = T[dr][mc + e];
    *(uint64_t*)&Wt[(size_t)(n0 + dr) * Kp + k0 + mc] = ((uint64_t*)tmp)[0];
    *(uint64_t*)&Wt[(size_t)(n0 + dr) * Kp + k0 + mc + 4] = ((uint64_t*)tmp)[1];
  }
}

// ------- GEMM, 8-phase (T2+T3+T4+T5): BN=256, BK=64, 2 K-tiles/iter, 512 thr -------
template <int BM, bool F32OUT>
__global__ __launch_bounds__(512, 1) void gemm8(const uint16_t* __restrict__ A, int lda,
                                                const uint16_t* __restrict__ Bt,
                                                void* __restrict__ Cv, int ldc, int K) {
  constexpr int MF = BM / 32;
  constexpr int MH = MF / 2;
  constexpr int AL = BM / 128;
  constexpr int ABYTES = BM * 128;
  __shared__ char lds[2 * BM * 128 + 2 * 256 * 128];
  char* const LB = lds + 2 * ABYTES;
  const int tid = threadIdx.x;
  const int lane = tid & 63;
  const int lr = lane & 15, lgb = (lane >> 4) * 16;
  const int wid = tid >> 6;
  const int g = wid >> 2;
  const int wc = (wid & 3) * 64;
  const int rA0 = g * (BM / 2) + lr;
  const int rB0 = wc + lr;
  const size_t row0 = (size_t)blockIdx.y * BM, col0 = (size_t)blockIdx.x * 256;
  const char* Agb = (const char*)(A + row0 * lda);
  const char* Btb = (const char*)(Bt + col0 * K);
  const size_t ldab = (size_t)lda * 2;
  const size_t ldbb = (size_t)K * 2;
  const int nk = K >> 6;
  const int ni = nk >> 1;

  f32x4 acc[MF][4] = {};
  bf16x8 aF[MH][2], bF[4][2];

  auto stageA = [&](int kt, int buf, int hf) {
#pragma unroll
    for (int j = 0; j < AL; ++j) {
      int c = j * 512 + tid;
      int cl = c ^ (((c >> 5) & 1) << 1);
      int row = hf * (BM / 2) + (cl >> 3);
      gl_lds16(Agb + (size_t)row * ldab + (size_t)kt * 128 + (cl & 7) * 16,
               lds + buf * ABYTES + hf * (ABYTES / 2) + (j * 512 + (tid & 0x1C0)) * 16);
    }
  };
  auto stageB = [&](int kt, int buf, int hf) {
#pragma unroll
    for (int j = 0; j < 2; ++j) {
      int c = j * 512 + tid;
      int cl = c ^ (((c >> 5) & 1) << 1);
      int row = hf * 128 + (cl >> 3);
      gl_lds16(Btb + (size_t)row * ldbb + (size_t)kt * 128 + (cl & 7) * 16,
               LB + buf * 32768 + hf * 16384 + (j * 512 + (tid & 0x1C0)) * 16);
    }
  };
  auto ldAm = [&](int buf, int mb) {
#pragma unroll
    for (int m = 0; m < MH; ++m) {
      int r = rA0 + (mb + m) * 16;
      int ro = r * 128;
      int sw = ((r >> 2) & 1) << 5;
#pragma unroll
      for (int kk = 0; kk < 2; ++kk)
        aF[m][kk] = *(const bf16x8*)(lds + buf * ABYTES + ((ro + kk * 64 + lgb) ^ sw));
    }
  };
  auto ldBn = [&](int buf, int nb) {
#pragma unroll
    for (int n = 0; n < 2; ++n) {
      int r = rB0 + (nb + n) * 16;
      int ro = r * 128;
      int sw = ((r >> 2) & 1) << 5;
#pragma unroll
      for (int kk = 0; kk < 2; ++kk)
        bF[nb + n][kk] = *(const bf16x8*)(LB + buf * 32768 + ((ro + kk * 64 + lgb) ^ sw));
    }
  };
  auto mmac = [&](int mb, int nb) {
#pragma unroll
    for (int m = 0; m < MH; ++m)
#pragma unroll
      for (int n = 0; n < 2; ++n)
#pragma unroll
        for (int kk = 0; kk < 2; ++kk)
          acc[mb + m][nb + n] = mfma16(aF[m][kk], bF[nb + n][kk], acc[mb + m][nb + n]);
  };

  stageA(0, 0, 0); stageA(0, 0, 1); stageB(0, 0, 0); stageB(0, 0, 1);
  stageB(1, 1, 0); stageB(1, 1, 1);
  WV4; BARX;

  for (int i = 0; i < ni; ++i) {
    const int t1 = 2 * i + 1;
    const int tn = (2 * i + 2 < nk) ? 2 * i + 2 : nk - 1;
    const int tn1 = (2 * i + 3 < nk) ? 2 * i + 3 : nk - 1;
    ldAm(0, 0); ldBn(0, 0); stageA(t1, 1, 0);
    BARX; WLG0; PRIO1; mmac(0, 0); PRIO0; BARX;
    ldBn(0, 2); stageA(t1, 1, 1);
    BARX; WLG0; PRIO1; mmac(0, 2); PRIO0; BARX;
    ldAm(0, MH); stageB(tn, 0, 0);
    BARX; WLG0; PRIO1; mmac(MH, 0); PRIO0; BARX;
    stageB(tn, 0, 1);
    BARX; PRIO1; mmac(MH, 2); PRIO0; WV4; BARX;
    ldAm(1, 0); ldBn(1, 0); stageA(tn, 0, 0);
    BARX; WLG0; PRIO1; mmac(0, 0); PRIO0; BARX;
    ldBn(1, 2); stageA(tn, 0, 1);
    BARX; WLG0; PRIO1; mmac(0, 2); PRIO0; BARX;
    ldAm(1, MH); stageB(tn1, 1, 0);
    BARX; WLG0; PRIO1; mmac(MH, 0); PRIO0; BARX;
    stageB(tn1, 1, 1);
    BARX; PRIO1; mmac(MH, 2); PRIO0; WV4; BARX;
  }
  asm volatile("s_waitcnt vmcnt(0)" ::: "memory");

#pragma unroll
  for (int m = 0; m < MF; ++m)
#pragma unroll
    for (int n = 0; n < 4; ++n)
#pragma unroll
      for (int j = 0; j < 4; ++j) {
        size_t row = row0 + g * (BM / 2) + m * 16 + (lane >> 4) * 4 + j;
        size_t col = col0 + wc + n * 16 + lr;
        if (F32OUT)
          ((float*)Cv)[row * ldc + col] = acc[m][n][j];
        else
          ((uint16_t*)Cv)[row * ldc + col] = f2b(acc[m][n][j]);
      }
}

// ------- GEMM dual, 8-phase BM=256: BOTH up-projections in one 448-block launch -------
__global__ __launch_bounds__(512, 1) void gemm8up(const uint16_t* __restrict__ cdA, int lda,
                                                  const uint16_t* __restrict__ wukv,
                                                  const uint16_t* __restrict__ wuqr,
                                                  uint16_t* __restrict__ cukv,
                                                  uint16_t* __restrict__ cuqr, int K) {
  constexpr int BM = 256;
  constexpr int MF = 8, MH = 4, AL = 2;
  constexpr int ABYTES = BM * 128;
  __shared__ char lds[2 * BM * 128 + 2 * 256 * 128];
  char* const LB = lds + 2 * ABYTES;
  const int tid = threadIdx.x;
  const int lane = tid & 63;
  const int lr = lane & 15, lgb = (lane >> 4) * 16;
  const int wid = tid >> 6;
  const int g = wid >> 2;
  const int wc = (wid & 3) * 64;
  const int rA0 = g * (BM / 2) + lr;
  const int rB0 = wc + lr;
  const bool second = blockIdx.x >= 16;
  const int xl = second ? blockIdx.x - 16 : blockIdx.x;
  const uint16_t* A = second ? cdA + 768 : cdA;
  const uint16_t* Bt = second ? wuqr : wukv;
  uint16_t* Cv = second ? cuqr : cukv;
  const int ldc = second ? 3072 : 4096;
  const size_t row0 = (size_t)blockIdx.y * BM, col0 = (size_t)xl * 256;
  const char* Agb = (const char*)(A + row0 * lda);
  const char* Btb = (const char*)(Bt + col0 * K);
  const size_t ldab = (size_t)lda * 2;
  const size_t ldbb = (size_t)K * 2;
  const int nk = K >> 6;
  const int ni = nk >> 1;

  f32x4 acc[MF][4] = {};
  bf16x8 aF[MH][2], bF[4][2];

  auto stageA = [&](int kt, int buf, int hf) {
#pragma unroll
    for (int j = 0; j < AL; ++j) {
      int c = j * 512 + tid;
      int cl = c ^ (((c >> 5) & 1) << 1);
      int row = hf * (BM / 2) + (cl >> 3);
      gl_lds16(Agb + (size_t)row * ldab + (size_t)kt * 128 + (cl & 7) * 16,
               lds + buf * ABYTES + hf * (ABYTES / 2) + (j * 512 + (tid & 0x1C0)) * 16);
    }
  };
  auto stageB = [&](int kt, int buf, int hf) {
#pragma unroll
    for (int j = 0; j < 2; ++j) {
      int c = j * 512 + tid;
      int cl = c ^ (((c >> 5) & 1) << 1);
      int row = hf * 128 + (cl >> 3);
      gl_lds16(Btb + (size_t)row * ldbb + (size_t)kt * 128 + (cl & 7) * 16,
               LB + buf * 32768 + hf * 16384 + (j * 512 + (tid & 0x1C0)) * 16);
    }
  };
  auto ldAm = [&](int buf, int mb) {
#pragma unroll
    for (int m = 0; m < MH; ++m) {
      int r = rA0 + (mb + m) * 16;
      int ro = r * 128;
      int sw = ((r >> 2) & 1) << 5;
#pragma unroll
      for (int kk = 0; kk < 2; ++kk)
        aF[m][kk] = *(const bf16x8*)(lds + buf * ABYTES + ((ro + kk * 64 + lgb) ^ sw));
    }
  };
  auto ldBn = [&](int buf, int nb) {
#pragma unroll
    for (int n = 0; n < 2; ++n) {
      int r = rB0 + (nb + n) * 16;
      int ro = r * 128;
      int sw = ((r >> 2) & 1) << 5;
#pragma unroll
      for (int kk = 0; kk < 2; ++kk)
        bF[nb + n][kk] = *(const bf16x8*)(LB + buf * 32768 + ((ro + kk * 64 + lgb) ^ sw));
    }
  };
  auto mmac = [&](int mb, int nb) {
#pragma unroll
    for (int m = 0; m < MH; ++m)
#pragma unroll
      for (int n = 0; n < 2; ++n)
#pragma unroll
        for (int kk = 0; kk < 2; ++kk)
          acc[mb + m][nb + n] = mfma16(aF[m][kk], bF[nb + n][kk], acc[mb + m][nb + n]);
  };

  stageA(0, 0, 0); stageA(0, 0, 1); stageB(0, 0, 0); stageB(0, 0, 1);
  stageB(1, 1, 0); stageB(1, 1, 1);
  WV4; BARX;

  for (int i = 0; i < ni; ++i) {
    const int t1 = 2 * i + 1;
    const int tn = (2 * i + 2 < nk) ? 2 * i + 2 : nk - 1;
    const int tn1 = (2 * i + 3 < nk) ? 2 * i + 3 : nk - 1;
    ldAm(0, 0); ldBn(0, 0); stageA(t1, 1, 0);
    BARX; WLG0; PRIO1; mmac(0, 0); PRIO0; BARX;
    ldBn(0, 2); stageA(t1, 1, 1);
    BARX; WLG0; PRIO1; mmac(0, 2); PRIO0; BARX;
    ldAm(0, MH); stageB(tn, 0, 0);
    BARX; WLG0; PRIO1; mmac(MH, 0); PRIO0; BARX;
    stageB(tn, 0, 1);
    BARX; PRIO1; mmac(MH, 2); PRIO0; WV4; BARX;
    ldAm(1, 0); ldBn(1, 0); stageA(tn, 0, 0);
    BARX; WLG0; PRIO1; mmac(0, 0); PRIO0; BARX;
    ldBn(1, 2); stageA(tn, 0, 1);
    BARX; WLG0; PRIO1; mmac(0, 2); PRIO0; BARX;
    ldAm(1, MH); stageB(tn1, 1, 0);
    BARX; WLG0; PRIO1; mmac(MH, 0); PRIO0; BARX;
    stageB(tn1, 1, 1);
    BARX; PRIO1; mmac(MH, 2); PRIO0; WV4; BARX;
  }
  asm volatile("s_waitcnt vmcnt(0)" ::: "memory");

#pragma unroll
  for (int m = 0; m < MF; ++m)
#pragma unroll
    for (int n = 0; n < 4; ++n)
#pragma unroll
      for (int j = 0; j < 4; ++j) {
        size_t row = row0 + g * (BM / 2) + m * 16 + (lane >> 4) * 4 + j;
        size_t col = col0 + wc + n * 16 + lr;
        Cv[row * ldc + col] = f2b(acc[m][n][j]);
      }
}

// ------- fused misc: rope_k (cd) + rope_q (cuqr) + vtrans (cukv -> vt) -------
__global__ void misc_kernel(uint16_t* __restrict__ cd, uint16_t* __restrict__ cuqr,
                            const uint16_t* __restrict__ cukv, uint16_t* __restrict__ vt) {
  const int bid = blockIdx.x;
  const int t = threadIdx.x;
  if (bid < 512) {  // rope_k: cols 1536..1599 of CD (ld 1792)
    int id = bid * 256 + t;
    int row = id >> 5, i = id & 31;
    int pos = row & 2047;
    float invf = exp2f(-13.287712379549449f * (float)i / 32.f);
    float ang = (float)pos * invf;
    float s, c;
    sincosf(ang, &s, &c);
    size_t base = (size_t)row * 1792 + 1536 + 2 * i;
    float x1 = b2f(cd[base]), x2 = b2f(cd[base + 1]);
    cd[base] = f2b(x1 * c - x2 * s);
    cd[base + 1] = f2b(x1 * s + x2 * c);
    return;
  }
  if (bid < 8704) {  // rope_q: cols 2048.. of CUQR (ld 3072)
    int id = (bid - 512) * 256 + t;
    int row = id >> 9;
    int rem = id & 511;
    int h = rem >> 5, i = rem & 31;
    int pos = row & 2047;
    float invf = exp2f(-13.287712379549449f * (float)i / 32.f);
    float ang = (float)pos * invf;
    float s, c;
    sincosf(ang, &s, &c);
    size_t base = (size_t)row * 3072 + 2048 + h * 64 + 2 * i;
    float x1 = b2f(cuqr[base]), x2 = b2f(cuqr[base + 1]);
    cuqr[base] = f2b(x1 * c - x2 * s);
    cuqr[base + 1] = f2b(x1 * s + x2 * c);
    return;
  }
  // vtrans: 2048 blocks
  const int idx = bid - 8704;
  const int mt = idx & 31, dt = (idx >> 5) & 1, bh = idx >> 6;
  const int b = bh >> 4, h = bh & 15;
  const int m0 = mt * 64, d0 = dt * 64;
  __shared__ uint16_t T[64][72];
#pragma unroll
  for (int p = 0; p < 2; ++p) {
    int r = p * 32 + (t >> 3), c8 = (t & 7) * 8;
    const uint16_t* s = &cukv[((size_t)(b * 2048 + m0 + r)) * 4096 + 2048 + h * 128 + d0 + c8];
    uint16_t tmp[8];
    ((uint64_t*)tmp)[0] = ((const uint64_t*)s)[0];
    ((uint64_t*)tmp)[1] = ((const uint64_t*)s)[1];
#pragma unroll
    for (int e = 0; e < 8; ++e) T[c8 + e][r] = tmp[e];
  }
  __syncthreads();
#pragma unroll
  for (int p = 0; p < 2; ++p) {
    int dr = p * 32 + (t >> 3), mc = (t & 7) * 8;
    uint16_t tmp[8];
#pragma unroll
    for (int e = 0; e < 8; ++e) tmp[e] = T[dr][mc + e];
    uint16_t* dstp = &vt[((size_t)(bh * 128 + d0 + dr)) * 2048 + m0 + mc];
    ((uint64_t*)dstp)[0] = ((uint64_t*)tmp)[0];
    ((uint64_t*)dstp)[1] = ((uint64_t*)tmp)[1];
  }
}

// ---------------- causal flash attention: TRUE 2 blocks/CU ----------------
// R12 body; LDS 80KB (K dbuf 2x24K, V SINGLE 16K, P 16K) -> 2 blocks co-resident.
// Grid 512, one qt/block; co-resident pair (bid, bid+256) shares bh with
// complementary qt (k, 15-k) -> 34 iters/CU uniform. Extra lgkm-only barrier
// between PV-reads and V-write (window = 2 ds_writes) is covered by the co-block.
__global__ __launch_bounds__(512, 2) void attn_kernel(const uint16_t* __restrict__ cuqr,
                                                      const uint16_t* __restrict__ cukv,
                                                      const uint16_t* __restrict__ cd,
                                                      const uint16_t* __restrict__ vt,
                                                      uint16_t* __restrict__ obuf) {
  __shared__ uint16_t Ks[2][64 * 192];  // 2 x 24KB
  __shared__ uint16_t Vs[128 * 64];     // 16KB (single buffer)
  __shared__ uint16_t Ps[8 * 16 * 64];  // 16KB
  const int tid = threadIdx.x;
  const int wid = tid >> 6, lane = tid & 63;
  const int lr = lane & 15, lg = lane >> 4;
  const int bid = blockIdx.x;
  const int cpair = bid >> 8, r0 = bid & 255;
  const int rp = (r0 & 7) * 32 + (r0 >> 3);  // XCD chunking
  const int bh = rp >> 3;
  const int qtl = rp & 7;
  const int qt = cpair ? (15 - qtl) : qtl;
  const int b = bh >> 4, h = bh & 15;
  const float sc2 = 0.07216878364870323f * 1.4426950408889634f;

  const char* Kcb = (const char*)cukv + (size_t)b * 2048 * 8192 + h * 256;
  const char* Krb = (const char*)cd + (size_t)b * 2048 * 3584 + 3072;
  const char* Vb = (const char*)vt + (size_t)bh * 524288;
  char* const Ks0 = (char*)Ks[0];
  char* const VsB = (char*)Vs;
  char* PwB = (char*)(Ps + wid * 1024);

  const char* kp[3];
  size_t kstep[3];
  int klds[3];
#pragma unroll
  for (int i = 0; i < 3; ++i) {
    int c = i * 512 + tid;  // 1536 chunks = 64 rows x 24 x 16B
    int rr = c / 24, c16 = c % 24;
    klds[i] = rr * 384 + ((c16 * 16) ^ ((rr & 7) << 4));
    if (c16 < 16) {
      kp[i] = Kcb + (size_t)rr * 8192 + c16 * 16;
      kstep[i] = (size_t)64 * 8192;
    } else {
      kp[i] = Krb + (size_t)rr * 3584 + (c16 - 16) * 16;
      kstep[i] = (size_t)64 * 3584;
    }
  }
  const char* vp[2];
  int vlds[2];
#pragma unroll
  for (int i = 0; i < 2; ++i) {
    int c = i * 512 + tid;  // 1024 chunks = 128 rows x 8 x 16B
    int d = c >> 3, c16 = c & 7;
    vlds[i] = d * 128 + ((c16 * 16) ^ ((d & 7) << 4));
    vp[i] = Vb + (size_t)d * 4096 + c16 * 16;
  }

  const int q0 = qt * 128;
  const int nt = 2 * (qt + 1);
  const int qrow = q0 + wid * 16 + lr;
  bf16x8 qf[6];
  {
    const char* Qcp = (const char*)cuqr + (size_t)(b * 2048 + qrow) * 6144 + h * 256 + lg * 16;
    const char* Qrp =
        (const char*)cuqr + (size_t)(b * 2048 + qrow) * 6144 + 4096 + h * 128 + lg * 16;
#pragma unroll
    for (int kb = 0; kb < 4; ++kb) qf[kb] = *(const bf16x8*)(Qcp + kb * 64);
#pragma unroll
    for (int kb = 0; kb < 2; ++kb) qf[4 + kb] = *(const bf16x8*)(Qrp + kb * 64);
  }
  f32x4 o[8] = {};
  float mrun[4], lrun[4];
#pragma unroll
  for (int j = 0; j < 4; ++j) { mrun[j] = -INFINITY; lrun[j] = 0.f; }

  bf16x8 kreg[3], vreg[2];
#pragma unroll
  for (int i = 0; i < 3; ++i) { kreg[i] = *(const bf16x8*)kp[i]; kp[i] += kstep[i]; }
#pragma unroll
  for (int i = 0; i < 2; ++i) { vreg[i] = *(const bf16x8*)vp[i]; vp[i] += 128; }
#pragma unroll
  for (int i = 0; i < 3; ++i) *(bf16x8*)(Ks0 + klds[i]) = kreg[i];
#pragma unroll
  for (int i = 0; i < 2; ++i) *(bf16x8*)(VsB + vlds[i]) = vreg[i];
  __syncthreads();

  for (int t = 0; t < nt; ++t) {
    const bool more = (t + 1 < nt);
    if (more) {  // issue next tile's global loads; compute covers latency
#pragma unroll
      for (int i = 0; i < 3; ++i) { kreg[i] = *(const bf16x8*)kp[i]; kp[i] += kstep[i]; }
#pragma unroll
      for (int i = 0; i < 2; ++i) { vreg[i] = *(const bf16x8*)vp[i]; vp[i] += 128; }
    }
    const int cb = t & 1;
    const char* KsB = Ks0 + cb * 24576;
    if (t * 64 <= q0 + wid * 16 + 15) {
      f32x4 s[4] = {};
      __builtin_amdgcn_s_setprio(1);
#pragma unroll
      for (int n = 0; n < 4; ++n) {
        int rr = n * 16 + lr;
        const char* kptr = KsB + rr * 384;
        int sw = (rr & 7) << 4;
#pragma unroll
        for (int kb = 0; kb < 6; ++kb)
          s[n] = mfma16(qf[kb], *(const bf16x8*)(kptr + ((kb * 64 + lg * 16) ^ sw)), s[n]);
      }
      __builtin_amdgcn_s_setprio(0);
      if (t * 64 + 63 > q0 + wid * 16) {  // diagonal: causal mask
#pragma unroll
        for (int n = 0; n < 4; ++n)
#pragma unroll
          for (int j = 0; j < 4; ++j)
            if (t * 64 + n * 16 + lr > q0 + wid * 16 + lg * 4 + j) s[n][j] = -INFINITY;
      }
      float pm[4];
#pragma unroll
      for (int j = 0; j < 4; ++j) {
        float v = fmaxf(fmaxf(s[0][j], s[1][j]), fmaxf(s[2][j], s[3][j]));
        v = fmaxf(v, __shfl_xor(v, 1));
        v = fmaxf(v, __shfl_xor(v, 2));
        v = fmaxf(v, __shfl_xor(v, 4));
        v = fmaxf(v, __shfl_xor(v, 8));
        pm[j] = v;
      }
      bool exceed = false;
#pragma unroll
      for (int j = 0; j < 4; ++j) exceed |= (pm[j] > mrun[j] + 76.8f);
      if (__any(exceed)) {
        float alpha[4];
#pragma unroll
        for (int j = 0; j < 4; ++j) {
          float mn = fmaxf(mrun[j], pm[j]);
          alpha[j] = exp2f((mrun[j] - mn) * sc2);
          mrun[j] = mn;
          lrun[j] *= alpha[j];
        }
#pragma unroll
        for (int n2 = 0; n2 < 8; ++n2)
#pragma unroll
          for (int j = 0; j < 4; ++j) o[n2][j] *= alpha[j];
      }
      float rs[4] = {0.f, 0.f, 0.f, 0.f};
#pragma unroll
      for (int n = 0; n < 4; ++n)
#pragma unroll
        for (int j = 0; j < 4; ++j) {
          float p = exp2f((s[n][j] - mrun[j]) * sc2);
          rs[j] += p;
          int row = lg * 4 + j;
          *(uint16_t*)(PwB + row * 128 + ((((n * 16 + lr)) * 2) ^ ((row & 7) << 4))) = f2b(p);
        }
#pragma unroll
      for (int j = 0; j < 4; ++j) lrun[j] += rs[j];
      __builtin_amdgcn_s_setprio(1);
#pragma unroll
      for (int kb2 = 0; kb2 < 2; ++kb2) {
        bf16x8 pa = *(const bf16x8*)(PwB + lr * 128 + ((kb2 * 64 + lg * 16) ^ ((lr & 7) << 4)));
#pragma unroll
        for (int n2 = 0; n2 < 8; ++n2) {
          int vr = n2 * 16 + lr;
          o[n2] = mfma16(
              pa, *(const bf16x8*)(VsB + vr * 128 + ((kb2 * 64 + lg * 16) ^ ((vr & 7) << 4))),
              o[n2]);
        }
      }
      __builtin_amdgcn_s_setprio(0);
    }
    if (more) {  // K dbuf target: last read in iter t-1, fenced by its final barrier
      char* KsN = Ks0 + (cb ^ 1) * 24576;
#pragma unroll
      for (int i = 0; i < 3; ++i) *(bf16x8*)(KsN + klds[i]) = kreg[i];
    }
    __syncthreads();  // all PV reads of Vs done
    if (more) {
#pragma unroll
      for (int i = 0; i < 2; ++i) *(bf16x8*)(VsB + vlds[i]) = vreg[i];
    }
    __syncthreads();  // V + K writes visible for iter t+1
  }
#pragma unroll
  for (int j = 0; j < 4; ++j) {
    float v = lrun[j];
    v += __shfl_xor(v, 1);
    v += __shfl_xor(v, 2);
    v += __shfl_xor(v, 4);
    v += __shfl_xor(v, 8);
    lrun[j] = v;
  }
  float inv[4];
#pragma unroll
  for (int j = 0; j < 4; ++j) inv[j] = 1.f / lrun[j];
#pragma unroll
  for (int n2 = 0; n2 < 8; ++n2)
#pragma unroll
    for (int j = 0; j < 4; ++j) {
      size_t row = (size_t)b * 2048 + q0 + wid * 16 + lg * 4 + j;
      size_t col = (size_t)h * 128 + n2 * 16 + lr;
      obuf[row * 2048 + col] = f2b(o[n2][j] * inv[j]);
    }
}

extern "C" void kernel_launch(void* const* d_in, const int* in_sizes, int n_in,
                              void* d_out, int out_size, void* d_ws, size_t ws_size,
                              hipStream_t stream) {
  (void)in_sizes; (void)n_in; (void)out_size; (void)ws_size;
  const float* x = (const float*)d_in[0];
  const float* Wdkv = (const float*)d_in[1];
  const float* Wuk = (const float*)d_in[2];
  const float* Wuv = (const float*)d_in[3];
  const float* Wkr = (const float*)d_in[4];
  const float* Wdq = (const float*)d_in[5];
  const float* Wuq = (const float*)d_in[6];
  const float* Wqr = (const float*)d_in[7];
  const float* Wo = (const float*)d_in[8];
  uint16_t* ws = (uint16_t*)d_ws;

  uint16_t* xb = ws + OFF_XB;
  uint16_t* obuf = ws + OFF_XB;    // reuse after x dead
  uint16_t* wd = ws + OFF_WD;
  uint16_t* wukv = ws + OFF_WUKV;
  uint16_t* wuqr = ws + OFF_WUQR;
  uint16_t* wo = ws + OFF_WO;
  uint16_t* cd = ws + OFF_CD;      // ld 1792
  uint16_t* cukv = ws + OFF_CUKV;
  uint16_t* cuqr = ws + OFF_CUQR;
  uint16_t* vtb = ws + OFF_VT;

  // fused preprocessing: cast + all weight transposes in one launch
  pre_kernel<<<11456, 256, 0, stream>>>(x, Wdkv, Wuk, Wuv, Wkr, Wdq, Wuq, Wqr, Wo, ws);
  // fused down-projection: (4096 x 1792) = xb * wd^T
  gemm8<128, false><<<dim3(7, 32), 512, 0, stream>>>(xb, 2048, wd, cd, 1792, 2048);
  // BOTH up-projections in one 448-block launch
  gemm8up<<<dim3(28, 16), 512, 0, stream>>>(cd, 1792, wukv, wuqr, cukv, cuqr, 768);
  // fused rope_k + rope_q + vtrans
  misc_kernel<<<10752, 256, 0, stream>>>(cd, cuqr, cukv, vtb);
  // attention (grid 512, true 2 blocks/CU, complementary qt pairs)
  attn_kernel<<<512, 512, 0, stream>>>(cuqr, cukv, cd, vtb, obuf);
  // output projection -> d_out fp32
  gemm8<128, true><<<dim3(8, 32), 512, 0, stream>>>(obuf, 2048, wo, d_out, 2048, 2048);
}

// Round 21
// 262.698 us; speedup vs baseline: 1.1314x; 1.1314x over previous
//
#include <hip/hip_runtime.h>
#include <stdint.h>

typedef __attribute__((ext_vector_type(8))) __bf16 bf16x8;
typedef __attribute__((ext_vector_type(4))) float f32x4;

#define DEVI static __device__ __forceinline__

DEVI uint16_t f2b(float f) {
  uint32_t u = __float_as_uint(f);
  u += 0x7FFFu + ((u >> 16) & 1u);
  return (uint16_t)(u >> 16);
}
DEVI float b2f(uint16_t b) { return __uint_as_float(((uint32_t)b) << 16); }

DEVI void gl_lds16(const void* g, void* l) {
  __builtin_amdgcn_global_load_lds((const __attribute__((address_space(1))) void*)g,
                                   (__attribute__((address_space(3))) void*)l, 16, 0, 0);
}

DEVI f32x4 mfma16(bf16x8 a, bf16x8 b, f32x4 c) {
  return __builtin_amdgcn_mfma_f32_16x16x32_bf16(a, b, c, 0, 0, 0);
}

#define BARX asm volatile("s_barrier" ::: "memory")
#define WLG0 asm volatile("s_waitcnt lgkmcnt(0)" ::: "memory")
#define WV4 asm volatile("s_waitcnt vmcnt(4)" ::: "memory")
#define PRIO1 __builtin_amdgcn_s_setprio(1)
#define PRIO0 __builtin_amdgcn_s_setprio(0)

// ---------------- workspace layout (bf16 elements) ----------------
static constexpr size_t OFF_XB = 0;                       // 4096x2048 (reused as OBUF)
static constexpr size_t OFF_WD = 8388608;                 // 1792x2048 fused d-weights (pad rows zero)
static constexpr size_t OFF_WUKV = OFF_WD + 3670016;      // 4096x768
static constexpr size_t OFF_WUQR = OFF_WUKV + 3145728;    // 3072x768
static constexpr size_t OFF_WO = OFF_WUQR + 2359296;      // 2048x2048
static constexpr size_t OFF_CD = OFF_WO + 4194304;        // 4096x1792
static constexpr size_t OFF_CUKV = OFF_CD + 7340032;      // 4096x4096
static constexpr size_t OFF_CUQR = OFF_CUKV + 16777216;   // 4096x3072
static constexpr size_t OFF_VT = OFF_CUQR + 12582912;     // 32x128x2048

// ------- fused preprocessing: x cast + all 8 weight transposes (R11, measured-good) -------
__global__ void pre_kernel(const float* __restrict__ x, const float* __restrict__ Wdkv,
                           const float* __restrict__ Wuk, const float* __restrict__ Wuv,
                           const float* __restrict__ Wkr, const float* __restrict__ Wdq,
                           const float* __restrict__ Wuq, const float* __restrict__ Wqr,
                           const float* __restrict__ Wo, uint16_t* __restrict__ ws) {
  const int bid = blockIdx.x;
  const int t = threadIdx.x;
  if (bid >= 3264) {  // cast segment: 8192 blocks
    int id = (bid - 3264) * 256 + t;
    float4 v = ((const float4*)x)[id];
    uint16_t o[4] = {f2b(v.x), f2b(v.y), f2b(v.z), f2b(v.w)};
    *(uint64_t*)&ws[OFF_XB + (size_t)id * 4] = *(uint64_t*)o;
    return;
  }
  const float* W;
  uint16_t* Wt;
  int Kw, Nw, Kp, nx, rb;
  if (bid < 384) {
    W = Wdkv; Wt = ws + OFF_WD; Kw = 2048; Nw = 682; Kp = 2048; nx = 12; rb = bid;
  } else if (bid < 768) {
    W = Wdq; Wt = ws + OFF_WD + (size_t)768 * 2048; Kw = 2048; Nw = 682; Kp = 2048; nx = 12; rb = bid - 384;
  } else if (bid < 896) {
    W = Wkr; Wt = ws + OFF_WD + (size_t)1536 * 2048; Kw = 2048; Nw = 64; Kp = 2048; nx = 4; rb = bid - 768;
  } else if (bid < 1280) {
    W = Wuk; Wt = ws + OFF_WUKV; Kw = 682; Nw = 2048; Kp = 768; nx = 32; rb = bid - 896;
  } else if (bid < 1664) {
    W = Wuv; Wt = ws + OFF_WUKV + (size_t)2048 * 768; Kw = 682; Nw = 2048; Kp = 768; nx = 32; rb = bid - 1280;
  } else if (bid < 2048) {
    W = Wuq; Wt = ws + OFF_WUQR; Kw = 682; Nw = 2048; Kp = 768; nx = 32; rb = bid - 1664;
  } else if (bid < 2240) {
    W = Wqr; Wt = ws + OFF_WUQR + (size_t)2048 * 768; Kw = 682; Nw = 1024; Kp = 768; nx = 16; rb = bid - 2048;
  } else {
    W = Wo; Wt = ws + OFF_WO; Kw = 2048; Nw = 2048; Kp = 2048; nx = 32; rb = bid - 2240;
  }
  const int n0 = (rb % nx) * 64, k0 = (rb / nx) * 64;
  __shared__ uint16_t T[64][72];
#pragma unroll
  for (int p = 0; p < 2; ++p) {
    int r = p * 32 + (t >> 3);
    int c0 = (t & 7) * 8;
    int gr = k0 + r;
#pragma unroll
    for (int e = 0; e < 8; ++e) {
      int gc = n0 + c0 + e;
      float v = (gr < Kw && gc < Nw) ? W[(size_t)gr * Nw + gc] : 0.f;
      T[c0 + e][r] = f2b(v);
    }
  }
  __syncthreads();
#pragma unroll
  for (int p = 0; p < 2; ++p) {
    int dr = p * 32 + (t >> 3);
    int mc = (t & 7) * 8;
    uint16_t tmp[8];
#pragma unroll
    for (int e = 0; e < 8; ++e) tmp[e] = T[dr][mc + e];
    *(uint64_t*)&Wt[(size_t)(n0 + dr) * Kp + k0 + mc] = ((uint64_t*)tmp)[0];
    *(uint64_t*)&Wt[(size_t)(n0 + dr) * Kp + k0 + mc + 4] = ((uint64_t*)tmp)[1];
  }
}

// ------- GEMM, 8-phase (T2+T3+T4+T5): BN=256, BK=64, 2 K-tiles/iter, 512 thr -------
template <int BM, bool F32OUT>
__global__ __launch_bounds__(512, 1) void gemm8(const uint16_t* __restrict__ A, int lda,
                                                const uint16_t* __restrict__ Bt,
                                                void* __restrict__ Cv, int ldc, int K) {
  constexpr int MF = BM / 32;
  constexpr int MH = MF / 2;
  constexpr int AL = BM / 128;
  constexpr int ABYTES = BM * 128;
  __shared__ char lds[2 * BM * 128 + 2 * 256 * 128];
  char* const LB = lds + 2 * ABYTES;
  const int tid = threadIdx.x;
  const int lane = tid & 63;
  const int lr = lane & 15, lgb = (lane >> 4) * 16;
  const int wid = tid >> 6;
  const int g = wid >> 2;
  const int wc = (wid & 3) * 64;
  const int rA0 = g * (BM / 2) + lr;
  const int rB0 = wc + lr;
  const size_t row0 = (size_t)blockIdx.y * BM, col0 = (size_t)blockIdx.x * 256;
  const char* Agb = (const char*)(A + row0 * lda);
  const char* Btb = (const char*)(Bt + col0 * K);
  const size_t ldab = (size_t)lda * 2;
  const size_t ldbb = (size_t)K * 2;
  const int nk = K >> 6;
  const int ni = nk >> 1;

  f32x4 acc[MF][4] = {};
  bf16x8 aF[MH][2], bF[4][2];

  auto stageA = [&](int kt, int buf, int hf) {
#pragma unroll
    for (int j = 0; j < AL; ++j) {
      int c = j * 512 + tid;
      int cl = c ^ (((c >> 5) & 1) << 1);
      int row = hf * (BM / 2) + (cl >> 3);
      gl_lds16(Agb + (size_t)row * ldab + (size_t)kt * 128 + (cl & 7) * 16,
               lds + buf * ABYTES + hf * (ABYTES / 2) + (j * 512 + (tid & 0x1C0)) * 16);
    }
  };
  auto stageB = [&](int kt, int buf, int hf) {
#pragma unroll
    for (int j = 0; j < 2; ++j) {
      int c = j * 512 + tid;
      int cl = c ^ (((c >> 5) & 1) << 1);
      int row = hf * 128 + (cl >> 3);
      gl_lds16(Btb + (size_t)row * ldbb + (size_t)kt * 128 + (cl & 7) * 16,
               LB + buf * 32768 + hf * 16384 + (j * 512 + (tid & 0x1C0)) * 16);
    }
  };
  auto ldAm = [&](int buf, int mb) {
#pragma unroll
    for (int m = 0; m < MH; ++m) {
      int r = rA0 + (mb + m) * 16;
      int ro = r * 128;
      int sw = ((r >> 2) & 1) << 5;
#pragma unroll
      for (int kk = 0; kk < 2; ++kk)
        aF[m][kk] = *(const bf16x8*)(lds + buf * ABYTES + ((ro + kk * 64 + lgb) ^ sw));
    }
  };
  auto ldBn = [&](int buf, int nb) {
#pragma unroll
    for (int n = 0; n < 2; ++n) {
      int r = rB0 + (nb + n) * 16;
      int ro = r * 128;
      int sw = ((r >> 2) & 1) << 5;
#pragma unroll
      for (int kk = 0; kk < 2; ++kk)
        bF[nb + n][kk] = *(const bf16x8*)(LB + buf * 32768 + ((ro + kk * 64 + lgb) ^ sw));
    }
  };
  auto mmac = [&](int mb, int nb) {
#pragma unroll
    for (int m = 0; m < MH; ++m)
#pragma unroll
      for (int n = 0; n < 2; ++n)
#pragma unroll
        for (int kk = 0; kk < 2; ++kk)
          acc[mb + m][nb + n] = mfma16(aF[m][kk], bF[nb + n][kk], acc[mb + m][nb + n]);
  };

  stageA(0, 0, 0); stageA(0, 0, 1); stageB(0, 0, 0); stageB(0, 0, 1);
  stageB(1, 1, 0); stageB(1, 1, 1);
  WV4; BARX;

  for (int i = 0; i < ni; ++i) {
    const int t1 = 2 * i + 1;
    const int tn = (2 * i + 2 < nk) ? 2 * i + 2 : nk - 1;
    const int tn1 = (2 * i + 3 < nk) ? 2 * i + 3 : nk - 1;
    ldAm(0, 0); ldBn(0, 0); stageA(t1, 1, 0);
    BARX; WLG0; PRIO1; mmac(0, 0); PRIO0; BARX;
    ldBn(0, 2); stageA(t1, 1, 1);
    BARX; WLG0; PRIO1; mmac(0, 2); PRIO0; BARX;
    ldAm(0, MH); stageB(tn, 0, 0);
    BARX; WLG0; PRIO1; mmac(MH, 0); PRIO0; BARX;
    stageB(tn, 0, 1);
    BARX; PRIO1; mmac(MH, 2); PRIO0; WV4; BARX;
    ldAm(1, 0); ldBn(1, 0); stageA(tn, 0, 0);
    BARX; WLG0; PRIO1; mmac(0, 0); PRIO0; BARX;
    ldBn(1, 2); stageA(tn, 0, 1);
    BARX; WLG0; PRIO1; mmac(0, 2); PRIO0; BARX;
    ldAm(1, MH); stageB(tn1, 1, 0);
    BARX; WLG0; PRIO1; mmac(MH, 0); PRIO0; BARX;
    stageB(tn1, 1, 1);
    BARX; PRIO1; mmac(MH, 2); PRIO0; WV4; BARX;
  }
  asm volatile("s_waitcnt vmcnt(0)" ::: "memory");

#pragma unroll
  for (int m = 0; m < MF; ++m)
#pragma unroll
    for (int n = 0; n < 4; ++n)
#pragma unroll
      for (int j = 0; j < 4; ++j) {
        size_t row = row0 + g * (BM / 2) + m * 16 + (lane >> 4) * 4 + j;
        size_t col = col0 + wc + n * 16 + lr;
        if (F32OUT)
          ((float*)Cv)[row * ldc + col] = acc[m][n][j];
        else
          ((uint16_t*)Cv)[row * ldc + col] = f2b(acc[m][n][j]);
      }
}

// ------- GEMM dual, 8-phase BM=256: BOTH up-projections in one 448-block launch -------
// Plain pointer select per block; NO epilogue math on acc (R16 lesson: shfl on the
// accumulator forces it out of AGPRs under the VGPR cap -> spill catastrophe).
__global__ __launch_bounds__(512, 1) void gemm8up(const uint16_t* __restrict__ cdA, int lda,
                                                  const uint16_t* __restrict__ wukv,
                                                  const uint16_t* __restrict__ wuqr,
                                                  uint16_t* __restrict__ cukv,
                                                  uint16_t* __restrict__ cuqr, int K) {
  constexpr int BM = 256;
  constexpr int MF = 8, MH = 4, AL = 2;
  constexpr int ABYTES = BM * 128;
  __shared__ char lds[2 * BM * 128 + 2 * 256 * 128];
  char* const LB = lds + 2 * ABYTES;
  const int tid = threadIdx.x;
  const int lane = tid & 63;
  const int lr = lane & 15, lgb = (lane >> 4) * 16;
  const int wid = tid >> 6;
  const int g = wid >> 2;
  const int wc = (wid & 3) * 64;
  const int rA0 = g * (BM / 2) + lr;
  const int rB0 = wc + lr;
  const bool second = blockIdx.x >= 16;
  const int xl = second ? blockIdx.x - 16 : blockIdx.x;
  const uint16_t* A = second ? cdA + 768 : cdA;
  const uint16_t* Bt = second ? wuqr : wukv;
  uint16_t* Cv = second ? cuqr : cukv;
  const int ldc = second ? 3072 : 4096;
  const size_t row0 = (size_t)blockIdx.y * BM, col0 = (size_t)xl * 256;
  const char* Agb = (const char*)(A + row0 * lda);
  const char* Btb = (const char*)(Bt + col0 * K);
  const size_t ldab = (size_t)lda * 2;
  const size_t ldbb = (size_t)K * 2;
  const int nk = K >> 6;
  const int ni = nk >> 1;

  f32x4 acc[MF][4] = {};
  bf16x8 aF[MH][2], bF[4][2];

  auto stageA = [&](int kt, int buf, int hf) {
#pragma unroll
    for (int j = 0; j < AL; ++j) {
      int c = j * 512 + tid;
      int cl = c ^ (((c >> 5) & 1) << 1);
      int row = hf * (BM / 2) + (cl >> 3);
      gl_lds16(Agb + (size_t)row * ldab + (size_t)kt * 128 + (cl & 7) * 16,
               lds + buf * ABYTES + hf * (ABYTES / 2) + (j * 512 + (tid & 0x1C0)) * 16);
    }
  };
  auto stageB = [&](int kt, int buf, int hf) {
#pragma unroll
    for (int j = 0; j < 2; ++j) {
      int c = j * 512 + tid;
      int cl = c ^ (((c >> 5) & 1) << 1);
      int row = hf * 128 + (cl >> 3);
      gl_lds16(Btb + (size_t)row * ldbb + (size_t)kt * 128 + (cl & 7) * 16,
               LB + buf * 32768 + hf * 16384 + (j * 512 + (tid & 0x1C0)) * 16);
    }
  };
  auto ldAm = [&](int buf, int mb) {
#pragma unroll
    for (int m = 0; m < MH; ++m) {
      int r = rA0 + (mb + m) * 16;
      int ro = r * 128;
      int sw = ((r >> 2) & 1) << 5;
#pragma unroll
      for (int kk = 0; kk < 2; ++kk)
        aF[m][kk] = *(const bf16x8*)(lds + buf * ABYTES + ((ro + kk * 64 + lgb) ^ sw));
    }
  };
  auto ldBn = [&](int buf, int nb) {
#pragma unroll
    for (int n = 0; n < 2; ++n) {
      int r = rB0 + (nb + n) * 16;
      int ro = r * 128;
      int sw = ((r >> 2) & 1) << 5;
#pragma unroll
      for (int kk = 0; kk < 2; ++kk)
        bF[nb + n][kk] = *(const bf16x8*)(LB + buf * 32768 + ((ro + kk * 64 + lgb) ^ sw));
    }
  };
  auto mmac = [&](int mb, int nb) {
#pragma unroll
    for (int m = 0; m < MH; ++m)
#pragma unroll
      for (int n = 0; n < 2; ++n)
#pragma unroll
        for (int kk = 0; kk < 2; ++kk)
          acc[mb + m][nb + n] = mfma16(aF[m][kk], bF[nb + n][kk], acc[mb + m][nb + n]);
  };

  stageA(0, 0, 0); stageA(0, 0, 1); stageB(0, 0, 0); stageB(0, 0, 1);
  stageB(1, 1, 0); stageB(1, 1, 1);
  WV4; BARX;

  for (int i = 0; i < ni; ++i) {
    const int t1 = 2 * i + 1;
    const int tn = (2 * i + 2 < nk) ? 2 * i + 2 : nk - 1;
    const int tn1 = (2 * i + 3 < nk) ? 2 * i + 3 : nk - 1;
    ldAm(0, 0); ldBn(0, 0); stageA(t1, 1, 0);
    BARX; WLG0; PRIO1; mmac(0, 0); PRIO0; BARX;
    ldBn(0, 2); stageA(t1, 1, 1);
    BARX; WLG0; PRIO1; mmac(0, 2); PRIO0; BARX;
    ldAm(0, MH); stageB(tn, 0, 0);
    BARX; WLG0; PRIO1; mmac(MH, 0); PRIO0; BARX;
    stageB(tn, 0, 1);
    BARX; PRIO1; mmac(MH, 2); PRIO0; WV4; BARX;
    ldAm(1, 0); ldBn(1, 0); stageA(tn, 0, 0);
    BARX; WLG0; PRIO1; mmac(0, 0); PRIO0; BARX;
    ldBn(1, 2); stageA(tn, 0, 1);
    BARX; WLG0; PRIO1; mmac(0, 2); PRIO0; BARX;
    ldAm(1, MH); stageB(tn1, 1, 0);
    BARX; WLG0; PRIO1; mmac(MH, 0); PRIO0; BARX;
    stageB(tn1, 1, 1);
    BARX; PRIO1; mmac(MH, 2); PRIO0; WV4; BARX;
  }
  asm volatile("s_waitcnt vmcnt(0)" ::: "memory");

#pragma unroll
  for (int m = 0; m < MF; ++m)
#pragma unroll
    for (int n = 0; n < 4; ++n)
#pragma unroll
      for (int j = 0; j < 4; ++j) {
        size_t row = row0 + g * (BM / 2) + m * 16 + (lane >> 4) * 4 + j;
        size_t col = col0 + wc + n * 16 + lr;
        Cv[row * ldc + col] = f2b(acc[m][n][j]);
      }
}

// ------- fused misc: rope_k (cd) + rope_q (cuqr) + vtrans (cukv -> vt) -------
__global__ void misc_kernel(uint16_t* __restrict__ cd, uint16_t* __restrict__ cuqr,
                            const uint16_t* __restrict__ cukv, uint16_t* __restrict__ vt) {
  const int bid = blockIdx.x;
  const int t = threadIdx.x;
  if (bid < 512) {  // rope_k: cols 1536..1599 of CD (ld 1792)
    int id = bid * 256 + t;
    int row = id >> 5, i = id & 31;
    int pos = row & 2047;
    float invf = exp2f(-13.287712379549449f * (float)i / 32.f);
    float ang = (float)pos * invf;
    float s, c;
    sincosf(ang, &s, &c);
    size_t base = (size_t)row * 1792 + 1536 + 2 * i;
    float x1 = b2f(cd[base]), x2 = b2f(cd[base + 1]);
    cd[base] = f2b(x1 * c - x2 * s);
    cd[base + 1] = f2b(x1 * s + x2 * c);
    return;
  }
  if (bid < 8704) {  // rope_q: cols 2048.. of CUQR (ld 3072)
    int id = (bid - 512) * 256 + t;
    int row = id >> 9;
    int rem = id & 511;
    int h = rem >> 5, i = rem & 31;
    int pos = row & 2047;
    float invf = exp2f(-13.287712379549449f * (float)i / 32.f);
    float ang = (float)pos * invf;
    float s, c;
    sincosf(ang, &s, &c);
    size_t base = (size_t)row * 3072 + 2048 + h * 64 + 2 * i;
    float x1 = b2f(cuqr[base]), x2 = b2f(cuqr[base + 1]);
    cuqr[base] = f2b(x1 * c - x2 * s);
    cuqr[base + 1] = f2b(x1 * s + x2 * c);
    return;
  }
  // vtrans: 2048 blocks
  const int idx = bid - 8704;
  const int mt = idx & 31, dt = (idx >> 5) & 1, bh = idx >> 6;
  const int b = bh >> 4, h = bh & 15;
  const int m0 = mt * 64, d0 = dt * 64;
  __shared__ uint16_t T[64][72];
#pragma unroll
  for (int p = 0; p < 2; ++p) {
    int r = p * 32 + (t >> 3), c8 = (t & 7) * 8;
    const uint16_t* s = &cukv[((size_t)(b * 2048 + m0 + r)) * 4096 + 2048 + h * 128 + d0 + c8];
    uint16_t tmp[8];
    ((uint64_t*)tmp)[0] = ((const uint64_t*)s)[0];
    ((uint64_t*)tmp)[1] = ((const uint64_t*)s)[1];
#pragma unroll
    for (int e = 0; e < 8; ++e) T[c8 + e][r] = tmp[e];
  }
  __syncthreads();
#pragma unroll
  for (int p = 0; p < 2; ++p) {
    int dr = p * 32 + (t >> 3), mc = (t & 7) * 8;
    uint16_t tmp[8];
#pragma unroll
    for (int e = 0; e < 8; ++e) tmp[e] = T[dr][mc + e];
    uint16_t* dstp = &vt[((size_t)(bh * 128 + d0 + dr)) * 2048 + m0 + mc];
    ((uint64_t*)dstp)[0] = ((uint64_t*)tmp)[0];
    ((uint64_t*)dstp)[1] = ((uint64_t*)tmp)[1];
  }
}

// ---------------- causal flash attention (R12/R19 body, measured 97 us) ----------------
__global__ __launch_bounds__(512, 1) void attn_kernel(const uint16_t* __restrict__ cuqr,
                                                      const uint16_t* __restrict__ cukv,
                                                      const uint16_t* __restrict__ cd,
                                                      const uint16_t* __restrict__ vt,
                                                      uint16_t* __restrict__ obuf) {
  __shared__ uint16_t Ks[2][64 * 192];  // 2 x 24KB
  __shared__ uint16_t Vs[2][128 * 64];  // 2 x 16KB
  __shared__ uint16_t Ps[8 * 16 * 64];  // 16KB
  const int tid = threadIdx.x;
  const int wid = tid >> 6, lane = tid & 63;
  const int lr = lane & 15, lg = lane >> 4;
  const int bid = blockIdx.x;
  const int wg = (bid & 7) * 32 + (bid >> 3);
  const int pairi = wg & 7;
  const int bh = wg >> 3;
  const int b = bh >> 4, h = bh & 15;
  const float sc2 = 0.07216878364870323f * 1.4426950408889634f;

  const char* Kcb = (const char*)cukv + (size_t)b * 2048 * 8192 + h * 256;
  const char* Krb = (const char*)cd + (size_t)b * 2048 * 3584 + 3072;
  const char* Vb = (const char*)vt + (size_t)bh * 524288;
  char* const Ks0 = (char*)Ks[0];
  char* const Vs0 = (char*)Vs[0];
  char* PwB = (char*)(Ps + wid * 1024);

  const char* kbase[3];
  size_t kstep[3];
  int klds[3];
#pragma unroll
  for (int i = 0; i < 3; ++i) {
    int c = i * 512 + tid;  // 1536 chunks = 64 rows x 24 x 16B
    int r = c / 24, c16 = c % 24;
    klds[i] = r * 384 + ((c16 * 16) ^ ((r & 7) << 4));
    if (c16 < 16) {
      kbase[i] = Kcb + (size_t)r * 8192 + c16 * 16;
      kstep[i] = (size_t)64 * 8192;
    } else {
      kbase[i] = Krb + (size_t)r * 3584 + (c16 - 16) * 16;
      kstep[i] = (size_t)64 * 3584;
    }
  }
  const char* vbase[2];
  int vlds[2];
#pragma unroll
  for (int i = 0; i < 2; ++i) {
    int c = i * 512 + tid;  // 1024 chunks = 128 rows x 8 x 16B
    int d = c >> 3, c16 = c & 7;
    vlds[i] = d * 128 + ((c16 * 16) ^ ((d & 7) << 4));
    vbase[i] = Vb + (size_t)d * 4096 + c16 * 16;
  }

  for (int ph = 0; ph < 2; ++ph) {
    const int qt = ph ? (15 - pairi) : pairi;
    const int q0 = qt * 128;
    const int nt = 2 * (qt + 1);
    const int qrow = q0 + wid * 16 + lr;
    bf16x8 qf[6];
    {
      const char* Qcp = (const char*)cuqr + (size_t)(b * 2048 + qrow) * 6144 + h * 256 + lg * 16;
      const char* Qrp =
          (const char*)cuqr + (size_t)(b * 2048 + qrow) * 6144 + 4096 + h * 128 + lg * 16;
#pragma unroll
      for (int kb = 0; kb < 4; ++kb) qf[kb] = *(const bf16x8*)(Qcp + kb * 64);
#pragma unroll
      for (int kb = 0; kb < 2; ++kb) qf[4 + kb] = *(const bf16x8*)(Qrp + kb * 64);
    }
    f32x4 o[8] = {};
    float mrun[4], lrun[4];
#pragma unroll
    for (int j = 0; j < 4; ++j) { mrun[j] = -INFINITY; lrun[j] = 0.f; }

    const char* kp[3];
    const char* vp[2];
    bf16x8 kreg[3], vreg[2];
#pragma unroll
    for (int i = 0; i < 3; ++i) kp[i] = kbase[i];
#pragma unroll
    for (int i = 0; i < 2; ++i) vp[i] = vbase[i];
#pragma unroll
    for (int i = 0; i < 3; ++i) { kreg[i] = *(const bf16x8*)kp[i]; kp[i] += kstep[i]; }
#pragma unroll
    for (int i = 0; i < 2; ++i) { vreg[i] = *(const bf16x8*)vp[i]; vp[i] += 128; }
#pragma unroll
    for (int i = 0; i < 3; ++i) *(bf16x8*)(Ks0 + klds[i]) = kreg[i];
#pragma unroll
    for (int i = 0; i < 2; ++i) *(bf16x8*)(Vs0 + vlds[i]) = vreg[i];
    __syncthreads();

    for (int t = 0; t < nt; ++t) {
      const bool more = (t + 1 < nt);
      if (more) {
#pragma unroll
        for (int i = 0; i < 3; ++i) { kreg[i] = *(const bf16x8*)kp[i]; kp[i] += kstep[i]; }
#pragma unroll
        for (int i = 0; i < 2; ++i) { vreg[i] = *(const bf16x8*)vp[i]; vp[i] += 128; }
      }
      const int cb = t & 1;
      const char* KsB = Ks0 + cb * 24576;
      const char* VsB = Vs0 + cb * 16384;
      if (t * 64 <= q0 + wid * 16 + 15) {
        f32x4 s[4] = {};
        __builtin_amdgcn_s_setprio(1);
#pragma unroll
        for (int n = 0; n < 4; ++n) {
          int r = n * 16 + lr;
          const char* kptr = KsB + r * 384;
          int sw = (r & 7) << 4;
#pragma unroll
          for (int kb = 0; kb < 6; ++kb)
            s[n] = mfma16(qf[kb], *(const bf16x8*)(kptr + ((kb * 64 + lg * 16) ^ sw)), s[n]);
        }
        __builtin_amdgcn_s_setprio(0);
        if (t * 64 + 63 > q0 + wid * 16) {
#pragma unroll
          for (int n = 0; n < 4; ++n)
#pragma unroll
            for (int j = 0; j < 4; ++j)
              if (t * 64 + n * 16 + lr > q0 + wid * 16 + lg * 4 + j) s[n][j] = -INFINITY;
        }
        float pm[4];
#pragma unroll
        for (int j = 0; j < 4; ++j) {
          float v = fmaxf(fmaxf(s[0][j], s[1][j]), fmaxf(s[2][j], s[3][j]));
          v = fmaxf(v, __shfl_xor(v, 1));
          v = fmaxf(v, __shfl_xor(v, 2));
          v = fmaxf(v, __shfl_xor(v, 4));
          v = fmaxf(v, __shfl_xor(v, 8));
          pm[j] = v;
        }
        bool exceed = false;
#pragma unroll
        for (int j = 0; j < 4; ++j) exceed |= (pm[j] > mrun[j] + 76.8f);
        if (__any(exceed)) {
          float alpha[4];
#pragma unroll
          for (int j = 0; j < 4; ++j) {
            float mn = fmaxf(mrun[j], pm[j]);
            alpha[j] = exp2f((mrun[j] - mn) * sc2);
            mrun[j] = mn;
            lrun[j] *= alpha[j];
          }
#pragma unroll
          for (int n2 = 0; n2 < 8; ++n2)
#pragma unroll
            for (int j = 0; j < 4; ++j) o[n2][j] *= alpha[j];
        }
        float rs[4] = {0.f, 0.f, 0.f, 0.f};
#pragma unroll
        for (int n = 0; n < 4; ++n)
#pragma unroll
          for (int j = 0; j < 4; ++j) {
            float p = exp2f((s[n][j] - mrun[j]) * sc2);
            rs[j] += p;
            int row = lg * 4 + j;
            *(uint16_t*)(PwB + row * 128 + ((((n * 16 + lr)) * 2) ^ ((row & 7) << 4))) = f2b(p);
          }
#pragma unroll
        for (int j = 0; j < 4; ++j) lrun[j] += rs[j];
        __builtin_amdgcn_s_setprio(1);
#pragma unroll
        for (int kb2 = 0; kb2 < 2; ++kb2) {
          bf16x8 pa = *(const bf16x8*)(PwB + lr * 128 + ((kb2 * 64 + lg * 16) ^ ((lr & 7) << 4)));
#pragma unroll
          for (int n2 = 0; n2 < 8; ++n2) {
            int vr = n2 * 16 + lr;
            o[n2] = mfma16(
                pa, *(const bf16x8*)(VsB + vr * 128 + ((kb2 * 64 + lg * 16) ^ ((vr & 7) << 4))),
                o[n2]);
          }
        }
        __builtin_amdgcn_s_setprio(0);
      }
      if (more) {
        char* KsN = Ks0 + (cb ^ 1) * 24576;
        char* VsN = Vs0 + (cb ^ 1) * 16384;
#pragma unroll
        for (int i = 0; i < 3; ++i) *(bf16x8*)(KsN + klds[i]) = kreg[i];
#pragma unroll
        for (int i = 0; i < 2; ++i) *(bf16x8*)(VsN + vlds[i]) = vreg[i];
      }
      __syncthreads();
    }
#pragma unroll
    for (int j = 0; j < 4; ++j) {
      float v = lrun[j];
      v += __shfl_xor(v, 1);
      v += __shfl_xor(v, 2);
      v += __shfl_xor(v, 4);
      v += __shfl_xor(v, 8);
      lrun[j] = v;
    }
    float inv[4];
#pragma unroll
    for (int j = 0; j < 4; ++j) inv[j] = 1.f / lrun[j];
#pragma unroll
    for (int n2 = 0; n2 < 8; ++n2)
#pragma unroll
      for (int j = 0; j < 4; ++j) {
        size_t row = (size_t)b * 2048 + q0 + wid * 16 + lg * 4 + j;
        size_t col = (size_t)h * 128 + n2 * 16 + lr;
        obuf[row * 2048 + col] = f2b(o[n2][j] * inv[j]);
      }
  }
}

extern "C" void kernel_launch(void* const* d_in, const int* in_sizes, int n_in,
                              void* d_out, int out_size, void* d_ws, size_t ws_size,
                              hipStream_t stream) {
  (void)in_sizes; (void)n_in; (void)out_size; (void)ws_size;
  const float* x = (const float*)d_in[0];
  const float* Wdkv = (const float*)d_in[1];
  const float* Wuk = (const float*)d_in[2];
  const float* Wuv = (const float*)d_in[3];
  const float* Wkr = (const float*)d_in[4];
  const float* Wdq = (const float*)d_in[5];
  const float* Wuq = (const float*)d_in[6];
  const float* Wqr = (const float*)d_in[7];
  const float* Wo = (const float*)d_in[8];
  uint16_t* ws = (uint16_t*)d_ws;

  uint16_t* xb = ws + OFF_XB;
  uint16_t* obuf = ws + OFF_XB;    // reuse after x dead
  uint16_t* wd = ws + OFF_WD;
  uint16_t* wukv = ws + OFF_WUKV;
  uint16_t* wuqr = ws + OFF_WUQR;
  uint16_t* wo = ws + OFF_WO;
  uint16_t* cd = ws + OFF_CD;      // ld 1792
  uint16_t* cukv = ws + OFF_CUKV;
  uint16_t* cuqr = ws + OFF_CUQR;
  uint16_t* vtb = ws + OFF_VT;

  // fused preprocessing: cast + all weight transposes in one launch
  pre_kernel<<<11456, 256, 0, stream>>>(x, Wdkv, Wuk, Wuv, Wkr, Wdq, Wuq, Wqr, Wo, ws);
  // fused down-projection: (4096 x 1792) = xb * wd^T
  gemm8<128, false><<<dim3(7, 32), 512, 0, stream>>>(xb, 2048, wd, cd, 1792, 2048);
  // BOTH up-projections in one 448-block launch
  gemm8up<<<dim3(28, 16), 512, 0, stream>>>(cd, 1792, wukv, wuqr, cukv, cuqr, 768);
  // fused rope_k + rope_q + vtrans
  misc_kernel<<<10752, 256, 0, stream>>>(cd, cuqr, cukv, vtb);
  // attention (QBLK=128, uniform pairs, dbuf single-barrier)
  attn_kernel<<<256, 512, 0, stream>>>(cuqr, cukv, cd, vtb, obuf);
  // output projection -> d_out fp32
  gemm8<128, true><<<dim3(8, 32), 512, 0, stream>>>(obuf, 2048, wo, d_out, 2048, 2048);
}

// Round 22
// 260.451 us; speedup vs baseline: 1.1411x; 1.0086x over previous
//
#include <hip/hip_runtime.h>
#include <stdint.h>

typedef __attribute__((ext_vector_type(8))) __bf16 bf16x8;
typedef __attribute__((ext_vector_type(4))) float f32x4;

#define DEVI static __device__ __forceinline__

DEVI uint16_t f2b(float f) {
  uint32_t u = __float_as_uint(f);
  u += 0x7FFFu + ((u >> 16) & 1u);
  return (uint16_t)(u >> 16);
}
DEVI float b2f(uint16_t b) { return __uint_as_float(((uint32_t)b) << 16); }

DEVI void gl_lds16(const void* g, void* l) {
  __builtin_amdgcn_global_load_lds((const __attribute__((address_space(1))) void*)g,
                                   (__attribute__((address_space(3))) void*)l, 16, 0, 0);
}

DEVI f32x4 mfma16(bf16x8 a, bf16x8 b, f32x4 c) {
  return __builtin_amdgcn_mfma_f32_16x16x32_bf16(a, b, c, 0, 0, 0);
}

#define BARX asm volatile("s_barrier" ::: "memory")
#define WLG0 asm volatile("s_waitcnt lgkmcnt(0)" ::: "memory")
#define WV4 asm volatile("s_waitcnt vmcnt(4)" ::: "memory")
#define PRIO1 __builtin_amdgcn_s_setprio(1)
#define PRIO0 __builtin_amdgcn_s_setprio(0)

// ---------------- workspace layout (bf16 elements) ----------------
static constexpr size_t OFF_XB = 0;                       // 4096x2048 (reused as OBUF)
static constexpr size_t OFF_WD = 8388608;                 // 1792x2048 fused d-weights (pad rows zero)
static constexpr size_t OFF_WUKV = OFF_WD + 3670016;      // 4096x768
static constexpr size_t OFF_WUQR = OFF_WUKV + 3145728;    // 3072x768
static constexpr size_t OFF_WO = OFF_WUQR + 2359296;      // 2048x2048
static constexpr size_t OFF_CD = OFF_WO + 4194304;        // 4096x1792
static constexpr size_t OFF_CUKV = OFF_CD + 7340032;      // 4096x4096
static constexpr size_t OFF_CUQR = OFF_CUKV + 16777216;   // 4096x3072
static constexpr size_t OFF_VT = OFF_CUQR + 12582912;     // 32x128x2048

// ------- fused preprocessing: x cast + all 8 weight transposes (R11, measured-good) -------
__global__ void pre_kernel(const float* __restrict__ x, const float* __restrict__ Wdkv,
                           const float* __restrict__ Wuk, const float* __restrict__ Wuv,
                           const float* __restrict__ Wkr, const float* __restrict__ Wdq,
                           const float* __restrict__ Wuq, const float* __restrict__ Wqr,
                           const float* __restrict__ Wo, uint16_t* __restrict__ ws) {
  const int bid = blockIdx.x;
  const int t = threadIdx.x;
  if (bid >= 3264) {  // cast segment: 8192 blocks
    int id = (bid - 3264) * 256 + t;
    float4 v = ((const float4*)x)[id];
    uint16_t o[4] = {f2b(v.x), f2b(v.y), f2b(v.z), f2b(v.w)};
    *(uint64_t*)&ws[OFF_XB + (size_t)id * 4] = *(uint64_t*)o;
    return;
  }
  const float* W;
  uint16_t* Wt;
  int Kw, Nw, Kp, nx, rb;
  if (bid < 384) {
    W = Wdkv; Wt = ws + OFF_WD; Kw = 2048; Nw = 682; Kp = 2048; nx = 12; rb = bid;
  } else if (bid < 768) {
    W = Wdq; Wt = ws + OFF_WD + (size_t)768 * 2048; Kw = 2048; Nw = 682; Kp = 2048; nx = 12; rb = bid - 384;
  } else if (bid < 896) {
    W = Wkr; Wt = ws + OFF_WD + (size_t)1536 * 2048; Kw = 2048; Nw = 64; Kp = 2048; nx = 4; rb = bid - 768;
  } else if (bid < 1280) {
    W = Wuk; Wt = ws + OFF_WUKV; Kw = 682; Nw = 2048; Kp = 768; nx = 32; rb = bid - 896;
  } else if (bid < 1664) {
    W = Wuv; Wt = ws + OFF_WUKV + (size_t)2048 * 768; Kw = 682; Nw = 2048; Kp = 768; nx = 32; rb = bid - 1280;
  } else if (bid < 2048) {
    W = Wuq; Wt = ws + OFF_WUQR; Kw = 682; Nw = 2048; Kp = 768; nx = 32; rb = bid - 1664;
  } else if (bid < 2240) {
    W = Wqr; Wt = ws + OFF_WUQR + (size_t)2048 * 768; Kw = 682; Nw = 1024; Kp = 768; nx = 16; rb = bid - 2048;
  } else {
    W = Wo; Wt = ws + OFF_WO; Kw = 2048; Nw = 2048; Kp = 2048; nx = 32; rb = bid - 2240;
  }
  const int n0 = (rb % nx) * 64, k0 = (rb / nx) * 64;
  __shared__ uint16_t T[64][72];
#pragma unroll
  for (int p = 0; p < 2; ++p) {
    int r = p * 32 + (t >> 3);
    int c0 = (t & 7) * 8;
    int gr = k0 + r;
#pragma unroll
    for (int e = 0; e < 8; ++e) {
      int gc = n0 + c0 + e;
      float v = (gr < Kw && gc < Nw) ? W[(size_t)gr * Nw + gc] : 0.f;
      T[c0 + e][r] = f2b(v);
    }
  }
  __syncthreads();
#pragma unroll
  for (int p = 0; p < 2; ++p) {
    int dr = p * 32 + (t >> 3);
    int mc = (t & 7) * 8;
    uint16_t tmp[8];
#pragma unroll
    for (int e = 0; e < 8; ++e) tmp[e] = T[dr][mc + e];
    *(uint64_t*)&Wt[(size_t)(n0 + dr) * Kp + k0 + mc] = ((uint64_t*)tmp)[0];
    *(uint64_t*)&Wt[(size_t)(n0 + dr) * Kp + k0 + mc + 4] = ((uint64_t*)tmp)[1];
  }
}

// ------- GEMM, 8-phase (T2+T3+T4+T5): BN=256, BK=64, 2 K-tiles/iter, 512 thr -------
template <int BM, bool F32OUT>
__global__ __launch_bounds__(512, 1) void gemm8(const uint16_t* __restrict__ A, int lda,
                                                const uint16_t* __restrict__ Bt,
                                                void* __restrict__ Cv, int ldc, int K) {
  constexpr int MF = BM / 32;
  constexpr int MH = MF / 2;
  constexpr int AL = BM / 128;
  constexpr int ABYTES = BM * 128;
  __shared__ char lds[2 * BM * 128 + 2 * 256 * 128];
  char* const LB = lds + 2 * ABYTES;
  const int tid = threadIdx.x;
  const int lane = tid & 63;
  const int lr = lane & 15, lgb = (lane >> 4) * 16;
  const int wid = tid >> 6;
  const int g = wid >> 2;
  const int wc = (wid & 3) * 64;
  const int rA0 = g * (BM / 2) + lr;
  const int rB0 = wc + lr;
  const size_t row0 = (size_t)blockIdx.y * BM, col0 = (size_t)blockIdx.x * 256;
  const char* Agb = (const char*)(A + row0 * lda);
  const char* Btb = (const char*)(Bt + col0 * K);
  const size_t ldab = (size_t)lda * 2;
  const size_t ldbb = (size_t)K * 2;
  const int nk = K >> 6;
  const int ni = nk >> 1;

  f32x4 acc[MF][4] = {};
  bf16x8 aF[MH][2], bF[4][2];

  auto stageA = [&](int kt, int buf, int hf) {
#pragma unroll
    for (int j = 0; j < AL; ++j) {
      int c = j * 512 + tid;
      int cl = c ^ (((c >> 5) & 1) << 1);
      int row = hf * (BM / 2) + (cl >> 3);
      gl_lds16(Agb + (size_t)row * ldab + (size_t)kt * 128 + (cl & 7) * 16,
               lds + buf * ABYTES + hf * (ABYTES / 2) + (j * 512 + (tid & 0x1C0)) * 16);
    }
  };
  auto stageB = [&](int kt, int buf, int hf) {
#pragma unroll
    for (int j = 0; j < 2; ++j) {
      int c = j * 512 + tid;
      int cl = c ^ (((c >> 5) & 1) << 1);
      int row = hf * 128 + (cl >> 3);
      gl_lds16(Btb + (size_t)row * ldbb + (size_t)kt * 128 + (cl & 7) * 16,
               LB + buf * 32768 + hf * 16384 + (j * 512 + (tid & 0x1C0)) * 16);
    }
  };
  auto ldAm = [&](int buf, int mb) {
#pragma unroll
    for (int m = 0; m < MH; ++m) {
      int r = rA0 + (mb + m) * 16;
      int ro = r * 128;
      int sw = ((r >> 2) & 1) << 5;
#pragma unroll
      for (int kk = 0; kk < 2; ++kk)
        aF[m][kk] = *(const bf16x8*)(lds + buf * ABYTES + ((ro + kk * 64 + lgb) ^ sw));
    }
  };
  auto ldBn = [&](int buf, int nb) {
#pragma unroll
    for (int n = 0; n < 2; ++n) {
      int r = rB0 + (nb + n) * 16;
      int ro = r * 128;
      int sw = ((r >> 2) & 1) << 5;
#pragma unroll
      for (int kk = 0; kk < 2; ++kk)
        bF[nb + n][kk] = *(const bf16x8*)(LB + buf * 32768 + ((ro + kk * 64 + lgb) ^ sw));
    }
  };
  auto mmac = [&](int mb, int nb) {
#pragma unroll
    for (int m = 0; m < MH; ++m)
#pragma unroll
      for (int n = 0; n < 2; ++n)
#pragma unroll
        for (int kk = 0; kk < 2; ++kk)
          acc[mb + m][nb + n] = mfma16(aF[m][kk], bF[nb + n][kk], acc[mb + m][nb + n]);
  };

  stageA(0, 0, 0); stageA(0, 0, 1); stageB(0, 0, 0); stageB(0, 0, 1);
  stageB(1, 1, 0); stageB(1, 1, 1);
  WV4; BARX;

  for (int i = 0; i < ni; ++i) {
    const int t1 = 2 * i + 1;
    const int tn = (2 * i + 2 < nk) ? 2 * i + 2 : nk - 1;
    const int tn1 = (2 * i + 3 < nk) ? 2 * i + 3 : nk - 1;
    ldAm(0, 0); ldBn(0, 0); stageA(t1, 1, 0);
    BARX; WLG0; PRIO1; mmac(0, 0); PRIO0; BARX;
    ldBn(0, 2); stageA(t1, 1, 1);
    BARX; WLG0; PRIO1; mmac(0, 2); PRIO0; BARX;
    ldAm(0, MH); stageB(tn, 0, 0);
    BARX; WLG0; PRIO1; mmac(MH, 0); PRIO0; BARX;
    stageB(tn, 0, 1);
    BARX; PRIO1; mmac(MH, 2); PRIO0; WV4; BARX;
    ldAm(1, 0); ldBn(1, 0); stageA(tn, 0, 0);
    BARX; WLG0; PRIO1; mmac(0, 0); PRIO0; BARX;
    ldBn(1, 2); stageA(tn, 0, 1);
    BARX; WLG0; PRIO1; mmac(0, 2); PRIO0; BARX;
    ldAm(1, MH); stageB(tn1, 1, 0);
    BARX; WLG0; PRIO1; mmac(MH, 0); PRIO0; BARX;
    stageB(tn1, 1, 1);
    BARX; PRIO1; mmac(MH, 2); PRIO0; WV4; BARX;
  }
  asm volatile("s_waitcnt vmcnt(0)" ::: "memory");

#pragma unroll
  for (int m = 0; m < MF; ++m)
#pragma unroll
    for (int n = 0; n < 4; ++n)
#pragma unroll
      for (int j = 0; j < 4; ++j) {
        size_t row = row0 + g * (BM / 2) + m * 16 + (lane >> 4) * 4 + j;
        size_t col = col0 + wc + n * 16 + lr;
        if (F32OUT)
          ((float*)Cv)[row * ldc + col] = acc[m][n][j];
        else
          ((uint16_t*)Cv)[row * ldc + col] = f2b(acc[m][n][j]);
      }
}

// ------- GEMM dual, 8-phase BM=256: BOTH up-projections in one 448-block launch -------
__global__ __launch_bounds__(512, 1) void gemm8up(const uint16_t* __restrict__ cdA, int lda,
                                                  const uint16_t* __restrict__ wukv,
                                                  const uint16_t* __restrict__ wuqr,
                                                  uint16_t* __restrict__ cukv,
                                                  uint16_t* __restrict__ cuqr, int K) {
  constexpr int BM = 256;
  constexpr int MF = 8, MH = 4, AL = 2;
  constexpr int ABYTES = BM * 128;
  __shared__ char lds[2 * BM * 128 + 2 * 256 * 128];
  char* const LB = lds + 2 * ABYTES;
  const int tid = threadIdx.x;
  const int lane = tid & 63;
  const int lr = lane & 15, lgb = (lane >> 4) * 16;
  const int wid = tid >> 6;
  const int g = wid >> 2;
  const int wc = (wid & 3) * 64;
  const int rA0 = g * (BM / 2) + lr;
  const int rB0 = wc + lr;
  const bool second = blockIdx.x >= 16;
  const int xl = second ? blockIdx.x - 16 : blockIdx.x;
  const uint16_t* A = second ? cdA + 768 : cdA;
  const uint16_t* Bt = second ? wuqr : wukv;
  uint16_t* Cv = second ? cuqr : cukv;
  const int ldc = second ? 3072 : 4096;
  const size_t row0 = (size_t)blockIdx.y * BM, col0 = (size_t)xl * 256;
  const char* Agb = (const char*)(A + row0 * lda);
  const char* Btb = (const char*)(Bt + col0 * K);
  const size_t ldab = (size_t)lda * 2;
  const size_t ldbb = (size_t)K * 2;
  const int nk = K >> 6;
  const int ni = nk >> 1;

  f32x4 acc[MF][4] = {};
  bf16x8 aF[MH][2], bF[4][2];

  auto stageA = [&](int kt, int buf, int hf) {
#pragma unroll
    for (int j = 0; j < AL; ++j) {
      int c = j * 512 + tid;
      int cl = c ^ (((c >> 5) & 1) << 1);
      int row = hf * (BM / 2) + (cl >> 3);
      gl_lds16(Agb + (size_t)row * ldab + (size_t)kt * 128 + (cl & 7) * 16,
               lds + buf * ABYTES + hf * (ABYTES / 2) + (j * 512 + (tid & 0x1C0)) * 16);
    }
  };
  auto stageB = [&](int kt, int buf, int hf) {
#pragma unroll
    for (int j = 0; j < 2; ++j) {
      int c = j * 512 + tid;
      int cl = c ^ (((c >> 5) & 1) << 1);
      int row = hf * 128 + (cl >> 3);
      gl_lds16(Btb + (size_t)row * ldbb + (size_t)kt * 128 + (cl & 7) * 16,
               LB + buf * 32768 + hf * 16384 + (j * 512 + (tid & 0x1C0)) * 16);
    }
  };
  auto ldAm = [&](int buf, int mb) {
#pragma unroll
    for (int m = 0; m < MH; ++m) {
      int r = rA0 + (mb + m) * 16;
      int ro = r * 128;
      int sw = ((r >> 2) & 1) << 5;
#pragma unroll
      for (int kk = 0; kk < 2; ++kk)
        aF[m][kk] = *(const bf16x8*)(lds + buf * ABYTES + ((ro + kk * 64 + lgb) ^ sw));
    }
  };
  auto ldBn = [&](int buf, int nb) {
#pragma unroll
    for (int n = 0; n < 2; ++n) {
      int r = rB0 + (nb + n) * 16;
      int ro = r * 128;
      int sw = ((r >> 2) & 1) << 5;
#pragma unroll
      for (int kk = 0; kk < 2; ++kk)
        bF[nb + n][kk] = *(const bf16x8*)(LB + buf * 32768 + ((ro + kk * 64 + lgb) ^ sw));
    }
  };
  auto mmac = [&](int mb, int nb) {
#pragma unroll
    for (int m = 0; m < MH; ++m)
#pragma unroll
      for (int n = 0; n < 2; ++n)
#pragma unroll
        for (int kk = 0; kk < 2; ++kk)
          acc[mb + m][nb + n] = mfma16(aF[m][kk], bF[nb + n][kk], acc[mb + m][nb + n]);
  };

  stageA(0, 0, 0); stageA(0, 0, 1); stageB(0, 0, 0); stageB(0, 0, 1);
  stageB(1, 1, 0); stageB(1, 1, 1);
  WV4; BARX;

  for (int i = 0; i < ni; ++i) {
    const int t1 = 2 * i + 1;
    const int tn = (2 * i + 2 < nk) ? 2 * i + 2 : nk - 1;
    const int tn1 = (2 * i + 3 < nk) ? 2 * i + 3 : nk - 1;
    ldAm(0, 0); ldBn(0, 0); stageA(t1, 1, 0);
    BARX; WLG0; PRIO1; mmac(0, 0); PRIO0; BARX;
    ldBn(0, 2); stageA(t1, 1, 1);
    BARX; WLG0; PRIO1; mmac(0, 2); PRIO0; BARX;
    ldAm(0, MH); stageB(tn, 0, 0);
    BARX; WLG0; PRIO1; mmac(MH, 0); PRIO0; BARX;
    stageB(tn, 0, 1);
    BARX; PRIO1; mmac(MH, 2); PRIO0; WV4; BARX;
    ldAm(1, 0); ldBn(1, 0); stageA(tn, 0, 0);
    BARX; WLG0; PRIO1; mmac(0, 0); PRIO0; BARX;
    ldBn(1, 2); stageA(tn, 0, 1);
    BARX; WLG0; PRIO1; mmac(0, 2); PRIO0; BARX;
    ldAm(1, MH); stageB(tn1, 1, 0);
    BARX; WLG0; PRIO1; mmac(MH, 0); PRIO0; BARX;
    stageB(tn1, 1, 1);
    BARX; PRIO1; mmac(MH, 2); PRIO0; WV4; BARX;
  }
  asm volatile("s_waitcnt vmcnt(0)" ::: "memory");

#pragma unroll
  for (int m = 0; m < MF; ++m)
#pragma unroll
    for (int n = 0; n < 4; ++n)
#pragma unroll
      for (int j = 0; j < 4; ++j) {
        size_t row = row0 + g * (BM / 2) + m * 16 + (lane >> 4) * 4 + j;
        size_t col = col0 + wc + n * 16 + lr;
        Cv[row * ldc + col] = f2b(acc[m][n][j]);
      }
}

// ------- fused misc: rope_k (cd) + vtrans (cukv -> vt); rope_q fused into attn -------
__global__ void misc_kernel(uint16_t* __restrict__ cd, const uint16_t* __restrict__ cukv,
                            uint16_t* __restrict__ vt) {
  const int bid = blockIdx.x;
  const int t = threadIdx.x;
  if (bid < 512) {  // rope_k: cols 1536..1599 of CD (ld 1792)
    int id = bid * 256 + t;
    int row = id >> 5, i = id & 31;
    int pos = row & 2047;
    float invf = exp2f(-13.287712379549449f * (float)i / 32.f);
    float ang = (float)pos * invf;
    float s, c;
    sincosf(ang, &s, &c);
    size_t base = (size_t)row * 1792 + 1536 + 2 * i;
    float x1 = b2f(cd[base]), x2 = b2f(cd[base + 1]);
    cd[base] = f2b(x1 * c - x2 * s);
    cd[base + 1] = f2b(x1 * s + x2 * c);
    return;
  }
  // vtrans: 2048 blocks
  const int idx = bid - 512;
  const int mt = idx & 31, dt = (idx >> 5) & 1, bh = idx >> 6;
  const int b = bh >> 4, h = bh & 15;
  const int m0 = mt * 64, d0 = dt * 64;
  __shared__ uint16_t T[64][72];
#pragma unroll
  for (int p = 0; p < 2; ++p) {
    int r = p * 32 + (t >> 3), c8 = (t & 7) * 8;
    const uint16_t* s = &cukv[((size_t)(b * 2048 + m0 + r)) * 4096 + 2048 + h * 128 + d0 + c8];
    uint16_t tmp[8];
    ((uint64_t*)tmp)[0] = ((const uint64_t*)s)[0];
    ((uint64_t*)tmp)[1] = ((const uint64_t*)s)[1];
#pragma unroll
    for (int e = 0; e < 8; ++e) T[c8 + e][r] = tmp[e];
  }
  __syncthreads();
#pragma unroll
  for (int p = 0; p < 2; ++p) {
    int dr = p * 32 + (t >> 3), mc = (t & 7) * 8;
    uint16_t tmp[8];
#pragma unroll
    for (int e = 0; e < 8; ++e) tmp[e] = T[dr][mc + e];
    uint16_t* dstp = &vt[((size_t)(bh * 128 + d0 + dr)) * 2048 + m0 + mc];
    ((uint64_t*)dstp)[0] = ((uint64_t*)tmp)[0];
    ((uint64_t*)dstp)[1] = ((uint64_t*)tmp)[1];
  }
}

// ---------------- causal flash attention (R12/R19 loop body; RoPE-q fused into
// the Q-load prologue -- q_R read raw from cuqr, rotated in-register once/phase) --------
__global__ __launch_bounds__(512, 1) void attn_kernel(const uint16_t* __restrict__ cuqr,
                                                      const uint16_t* __restrict__ cukv,
                                                      const uint16_t* __restrict__ cd,
                                                      const uint16_t* __restrict__ vt,
                                                      uint16_t* __restrict__ obuf) {
  __shared__ uint16_t Ks[2][64 * 192];  // 2 x 24KB
  __shared__ uint16_t Vs[2][128 * 64];  // 2 x 16KB
  __shared__ uint16_t Ps[8 * 16 * 64];  // 16KB
  const int tid = threadIdx.x;
  const int wid = tid >> 6, lane = tid & 63;
  const int lr = lane & 15, lg = lane >> 4;
  const int bid = blockIdx.x;
  const int wg = (bid & 7) * 32 + (bid >> 3);
  const int pairi = wg & 7;
  const int bh = wg >> 3;
  const int b = bh >> 4, h = bh & 15;
  const float sc2 = 0.07216878364870323f * 1.4426950408889634f;

  const char* Kcb = (const char*)cukv + (size_t)b * 2048 * 8192 + h * 256;
  const char* Krb = (const char*)cd + (size_t)b * 2048 * 3584 + 3072;
  const char* Vb = (const char*)vt + (size_t)bh * 524288;
  char* const Ks0 = (char*)Ks[0];
  char* const Vs0 = (char*)Vs[0];
  char* PwB = (char*)(Ps + wid * 1024);

  const char* kbase[3];
  size_t kstep[3];
  int klds[3];
#pragma unroll
  for (int i = 0; i < 3; ++i) {
    int c = i * 512 + tid;  // 1536 chunks = 64 rows x 24 x 16B
    int r = c / 24, c16 = c % 24;
    klds[i] = r * 384 + ((c16 * 16) ^ ((r & 7) << 4));
    if (c16 < 16) {
      kbase[i] = Kcb + (size_t)r * 8192 + c16 * 16;
      kstep[i] = (size_t)64 * 8192;
    } else {
      kbase[i] = Krb + (size_t)r * 3584 + (c16 - 16) * 16;
      kstep[i] = (size_t)64 * 3584;
    }
  }
  const char* vbase[2];
  int vlds[2];
#pragma unroll
  for (int i = 0; i < 2; ++i) {
    int c = i * 512 + tid;  // 1024 chunks = 128 rows x 8 x 16B
    int d = c >> 3, c16 = c & 7;
    vlds[i] = d * 128 + ((c16 * 16) ^ ((d & 7) << 4));
    vbase[i] = Vb + (size_t)d * 4096 + c16 * 16;
  }

  for (int ph = 0; ph < 2; ++ph) {
    const int qt = ph ? (15 - pairi) : pairi;
    const int q0 = qt * 128;
    const int nt = 2 * (qt + 1);
    const int qrow = q0 + wid * 16 + lr;
    bf16x8 qf[6];
    {
      const char* Qcp = (const char*)cuqr + (size_t)(b * 2048 + qrow) * 6144 + h * 256 + lg * 16;
      const char* Qrp =
          (const char*)cuqr + (size_t)(b * 2048 + qrow) * 6144 + 4096 + h * 128 + lg * 16;
#pragma unroll
      for (int kb = 0; kb < 4; ++kb) qf[kb] = *(const bf16x8*)(Qcp + kb * 64);
#pragma unroll
      for (int kb = 0; kb < 2; ++kb) qf[4 + kb] = *(const bf16x8*)(Qrp + kb * 64);
      // fused RoPE on q_R (once per phase; pairs are adjacent elements in-vector)
#pragma unroll
      for (int kb = 0; kb < 2; ++kb) {
        uint16_t* qb = (uint16_t*)&qf[4 + kb];
#pragma unroll
        for (int j = 0; j < 4; ++j) {
          int fi = lg * 4 + kb * 16 + j;  // frequency index in [0,32)
          float invf = exp2f(-13.287712379549449f * (float)fi / 32.f);
          float ang = (float)qrow * invf;
          float sv, cv;
          sincosf(ang, &sv, &cv);
          float x1 = b2f(qb[2 * j]), x2 = b2f(qb[2 * j + 1]);
          qb[2 * j] = f2b(x1 * cv - x2 * sv);
          qb[2 * j + 1] = f2b(x1 * sv + x2 * cv);
        }
      }
    }
    f32x4 o[8] = {};
    float mrun[4], lrun[4];
#pragma unroll
    for (int j = 0; j < 4; ++j) { mrun[j] = -INFINITY; lrun[j] = 0.f; }

    const char* kp[3];
    const char* vp[2];
    bf16x8 kreg[3], vreg[2];
#pragma unroll
    for (int i = 0; i < 3; ++i) kp[i] = kbase[i];
#pragma unroll
    for (int i = 0; i < 2; ++i) vp[i] = vbase[i];
#pragma unroll
    for (int i = 0; i < 3; ++i) { kreg[i] = *(const bf16x8*)kp[i]; kp[i] += kstep[i]; }
#pragma unroll
    for (int i = 0; i < 2; ++i) { vreg[i] = *(const bf16x8*)vp[i]; vp[i] += 128; }
#pragma unroll
    for (int i = 0; i < 3; ++i) *(bf16x8*)(Ks0 + klds[i]) = kreg[i];
#pragma unroll
    for (int i = 0; i < 2; ++i) *(bf16x8*)(Vs0 + vlds[i]) = vreg[i];
    __syncthreads();

    for (int t = 0; t < nt; ++t) {
      const bool more = (t + 1 < nt);
      if (more) {
#pragma unroll
        for (int i = 0; i < 3; ++i) { kreg[i] = *(const bf16x8*)kp[i]; kp[i] += kstep[i]; }
#pragma unroll
        for (int i = 0; i < 2; ++i) { vreg[i] = *(const bf16x8*)vp[i]; vp[i] += 128; }
      }
      const int cb = t & 1;
      const char* KsB = Ks0 + cb * 24576;
      const char* VsB = Vs0 + cb * 16384;
      if (t * 64 <= q0 + wid * 16 + 15) {
        f32x4 s[4] = {};
        __builtin_amdgcn_s_setprio(1);
#pragma unroll
        for (int n = 0; n < 4; ++n) {
          int r = n * 16 + lr;
          const char* kptr = KsB + r * 384;
          int sw = (r & 7) << 4;
#pragma unroll
          for (int kb = 0; kb < 6; ++kb)
            s[n] = mfma16(qf[kb], *(const bf16x8*)(kptr + ((kb * 64 + lg * 16) ^ sw)), s[n]);
        }
        __builtin_amdgcn_s_setprio(0);
        if (t * 64 + 63 > q0 + wid * 16) {
#pragma unroll
          for (int n = 0; n < 4; ++n)
#pragma unroll
            for (int j = 0; j < 4; ++j)
              if (t * 64 + n * 16 + lr > q0 + wid * 16 + lg * 4 + j) s[n][j] = -INFINITY;
        }
        float pm[4];
#pragma unroll
        for (int j = 0; j < 4; ++j) {
          float v = fmaxf(fmaxf(s[0][j], s[1][j]), fmaxf(s[2][j], s[3][j]));
          v = fmaxf(v, __shfl_xor(v, 1));
          v = fmaxf(v, __shfl_xor(v, 2));
          v = fmaxf(v, __shfl_xor(v, 4));
          v = fmaxf(v, __shfl_xor(v, 8));
          pm[j] = v;
        }
        bool exceed = false;
#pragma unroll
        for (int j = 0; j < 4; ++j) exceed |= (pm[j] > mrun[j] + 76.8f);
        if (__any(exceed)) {
          float alpha[4];
#pragma unroll
          for (int j = 0; j < 4; ++j) {
            float mn = fmaxf(mrun[j], pm[j]);
            alpha[j] = exp2f((mrun[j] - mn) * sc2);
            mrun[j] = mn;
            lrun[j] *= alpha[j];
          }
#pragma unroll
          for (int n2 = 0; n2 < 8; ++n2)
#pragma unroll
            for (int j = 0; j < 4; ++j) o[n2][j] *= alpha[j];
        }
        float rs[4] = {0.f, 0.f, 0.f, 0.f};
#pragma unroll
        for (int n = 0; n < 4; ++n)
#pragma unroll
          for (int j = 0; j < 4; ++j) {
            float p = exp2f((s[n][j] - mrun[j]) * sc2);
            rs[j] += p;
            int row = lg * 4 + j;
            *(uint16_t*)(PwB + row * 128 + ((((n * 16 + lr)) * 2) ^ ((row & 7) << 4))) = f2b(p);
          }
#pragma unroll
        for (int j = 0; j < 4; ++j) lrun[j] += rs[j];
        __builtin_amdgcn_s_setprio(1);
#pragma unroll
        for (int kb2 = 0; kb2 < 2; ++kb2) {
          bf16x8 pa = *(const bf16x8*)(PwB + lr * 128 + ((kb2 * 64 + lg * 16) ^ ((lr & 7) << 4)));
#pragma unroll
          for (int n2 = 0; n2 < 8; ++n2) {
            int vr = n2 * 16 + lr;
            o[n2] = mfma16(
                pa, *(const bf16x8*)(VsB + vr * 128 + ((kb2 * 64 + lg * 16) ^ ((vr & 7) << 4))),
                o[n2]);
          }
        }
        __builtin_amdgcn_s_setprio(0);
      }
      if (more) {
        char* KsN = Ks0 + (cb ^ 1) * 24576;
        char* VsN = Vs0 + (cb ^ 1) * 16384;
#pragma unroll
        for (int i = 0; i < 3; ++i) *(bf16x8*)(KsN + klds[i]) = kreg[i];
#pragma unroll
        for (int i = 0; i < 2; ++i) *(bf16x8*)(VsN + vlds[i]) = vreg[i];
      }
      __syncthreads();
    }
#pragma unroll
    for (int j = 0; j < 4; ++j) {
      float v = lrun[j];
      v += __shfl_xor(v, 1);
      v += __shfl_xor(v, 2);
      v += __shfl_xor(v, 4);
      v += __shfl_xor(v, 8);
      lrun[j] = v;
    }
    float inv[4];
#pragma unroll
    for (int j = 0; j < 4; ++j) inv[j] = 1.f / lrun[j];
#pragma unroll
    for (int n2 = 0; n2 < 8; ++n2)
#pragma unroll
      for (int j = 0; j < 4; ++j) {
        size_t row = (size_t)b * 2048 + q0 + wid * 16 + lg * 4 + j;
        size_t col = (size_t)h * 128 + n2 * 16 + lr;
        obuf[row * 2048 + col] = f2b(o[n2][j] * inv[j]);
      }
  }
}

extern "C" void kernel_launch(void* const* d_in, const int* in_sizes, int n_in,
                              void* d_out, int out_size, void* d_ws, size_t ws_size,
                              hipStream_t stream) {
  (void)in_sizes; (void)n_in; (void)out_size; (void)ws_size;
  const float* x = (const float*)d_in[0];
  const float* Wdkv = (const float*)d_in[1];
  const float* Wuk = (const float*)d_in[2];
  const float* Wuv = (const float*)d_in[3];
  const float* Wkr = (const float*)d_in[4];
  const float* Wdq = (const float*)d_in[5];
  const float* Wuq = (const float*)d_in[6];
  const float* Wqr = (const float*)d_in[7];
  const float* Wo = (const float*)d_in[8];
  uint16_t* ws = (uint16_t*)d_ws;

  uint16_t* xb = ws + OFF_XB;
  uint16_t* obuf = ws + OFF_XB;    // reuse after x dead
  uint16_t* wd = ws + OFF_WD;
  uint16_t* wukv = ws + OFF_WUKV;
  uint16_t* wuqr = ws + OFF_WUQR;
  uint16_t* wo = ws + OFF_WO;
  uint16_t* cd = ws + OFF_CD;      // ld 1792
  uint16_t* cukv = ws + OFF_CUKV;
  uint16_t* cuqr = ws + OFF_CUQR;
  uint16_t* vtb = ws + OFF_VT;

  // fused preprocessing: cast + all weight transposes in one launch
  pre_kernel<<<11456, 256, 0, stream>>>(x, Wdkv, Wuk, Wuv, Wkr, Wdq, Wuq, Wqr, Wo, ws);
  // fused down-projection: (4096 x 1792) = xb * wd^T
  gemm8<128, false><<<dim3(7, 32), 512, 0, stream>>>(xb, 2048, wd, cd, 1792, 2048);
  // BOTH up-projections in one 448-block launch
  gemm8up<<<dim3(28, 16), 512, 0, stream>>>(cd, 1792, wukv, wuqr, cukv, cuqr, 768);
  // fused rope_k + vtrans (rope_q now applied inside attn's Q load)
  misc_kernel<<<2560, 256, 0, stream>>>(cd, cukv, vtb);
  // attention (QBLK=128, uniform pairs, dbuf single-barrier, fused rope_q)
  attn_kernel<<<256, 512, 0, stream>>>(cuqr, cukv, cd, vtb, obuf);
  // output projection -> d_out fp32
  gemm8<128, true><<<dim3(8, 32), 512, 0, stream>>>(obuf, 2048, wo, d_out, 2048, 2048);
}